// Round 4
// baseline (661.445 us; speedup 1.0000x reference)
//
#include <hip/hip_runtime.h>
#include <hip/hip_bf16.h>

#define RS 0.9999950000374998f  // 1/sqrt(1+1e-5)

__device__ __forceinline__ float eluf(float x) {
    return x > 0.0f ? x : expf(x) - 1.0f;
}

// ---------------------------------------------------------------------------
// Generic tiled f32 GEMM: out[r, c] = post(sum_k A[r,k] * W[k,c] + bias[c])
// post: ACT -> elu; BN -> *gamma/sqrt(1+eps) + beta
// rows multiple of 64, Ncols multiple of 64, Kdim multiple of 16.
// block 256, grid (rows/64, Ncols/64)
// ---------------------------------------------------------------------------
template <int ACT, int BN>
__global__ __launch_bounds__(256) void gemm_bias_act(
    const float* __restrict__ A, const float* __restrict__ W,
    const float* __restrict__ bias, const float* __restrict__ gamma,
    const float* __restrict__ beta, float* __restrict__ out,
    int Kdim, int Ncols) {
    __shared__ float As[16][64];
    __shared__ float Bs[16][64];
    const int tid = threadIdx.x;
    const int tx = tid & 15, ty = tid >> 4;
    const long row0 = (long)blockIdx.x * 64;
    const int col0 = blockIdx.y * 64;
    const int rA = tid >> 2, kqA = (tid & 3) << 2;
    const int kkB = tid >> 4, cqB = (tid & 15) << 2;
    float acc[4][4] = {};
    for (int k0 = 0; k0 < Kdim; k0 += 16) {
        const float4 av = *reinterpret_cast<const float4*>(
            A + (row0 + rA) * (long)Kdim + (k0 + kqA));
        const float4 bv = *reinterpret_cast<const float4*>(
            W + (long)(k0 + kkB) * Ncols + (col0 + cqB));
        As[kqA + 0][rA] = av.x;
        As[kqA + 1][rA] = av.y;
        As[kqA + 2][rA] = av.z;
        As[kqA + 3][rA] = av.w;
        *reinterpret_cast<float4*>(&Bs[kkB][cqB]) = bv;
        __syncthreads();
#pragma unroll
        for (int kk = 0; kk < 16; ++kk) {
            float a[4], b[4];
#pragma unroll
            for (int i = 0; i < 4; ++i) a[i] = As[kk][ty * 4 + i];
#pragma unroll
            for (int j = 0; j < 4; ++j) b[j] = Bs[kk][tx * 4 + j];
#pragma unroll
            for (int i = 0; i < 4; ++i)
#pragma unroll
                for (int j = 0; j < 4; ++j) acc[i][j] = fmaf(a[i], b[j], acc[i][j]);
        }
        __syncthreads();
    }
#pragma unroll
    for (int j = 0; j < 4; ++j) {
        const int col = col0 + tx * 4 + j;
        const float bb = bias[col];
        const float gs = BN ? gamma[col] * RS : 0.0f;
        const float bt = BN ? beta[col] : 0.0f;
#pragma unroll
        for (int i = 0; i < 4; ++i) {
            const long row = row0 + ty * 4 + i;
            float v = acc[i][j] + bb;
            if (ACT) v = eluf(v);
            if (BN) v = v * gs + bt;
            out[row * Ncols + col] = v;
        }
    }
}

// ---------------------------------------------------------------------------
// Setup: per point, gather neighbor coords, compute pts_local (store) and
// Xc[gp, o] = elu(sum_{d,k} pts_local[k,d] * xt_cW[o,d,k] + cb[o])  (store)
// 16 points per block, 256 threads. grid = 32768/16 = 2048.
// ---------------------------------------------------------------------------
__global__ __launch_bounds__(256) void setup_kernel(
    const float* __restrict__ rep_pts, const float* __restrict__ pts,
    const int* __restrict__ pts_idx, const float* __restrict__ xt_cW,
    const float* __restrict__ xt_cb, float* __restrict__ pts_local,
    float* __restrict__ Xc) {
    __shared__ float cwT[48][256];  // cwT[d*16+k][o] = xt_cW[o,d,k]
    __shared__ float pl2[16][48];   // pl2[pt][d*16+k]
    __shared__ float cb_s[256];
    const int tid = threadIdx.x;
    const long gp0 = (long)blockIdx.x * 16;
#pragma unroll
    for (int i = 0; i < 48; ++i) cwT[i][tid] = xt_cW[tid * 48 + i];
    cb_s[tid] = xt_cb[tid];
    {
        const int pt = tid >> 4, k = tid & 15;
        const long gp = gp0 + pt;
        const int n = (int)(gp >> 11);
        const int idx = pts_idx[gp * 32 + 2 * k];
        const float* ps = pts + ((long)n * 8192 + idx) * 3;
        const float* rs = rep_pts + gp * 3;
        float* plo = pts_local + gp * 48 + k * 3;
#pragma unroll
        for (int d = 0; d < 3; ++d) {
            const float v = ps[d] - rs[d];
            pl2[pt][d * 16 + k] = v;
            plo[d] = v;
        }
    }
    __syncthreads();
    const int o = tid;
    for (int pt = 0; pt < 16; ++pt) {
        float acc = cb_s[o];
#pragma unroll
        for (int i = 0; i < 48; ++i) acc = fmaf(pl2[pt][i], cwT[i][o], acc);
        Xc[(gp0 + pt) * 256 + o] = eluf(acc);
    }
}

// ---------------------------------------------------------------------------
// Final per-point stage, wave-per-point column-owner layout, v3.
// Block = 256 threads = 4 waves = 4 points. grid = 32768/4 = 8192.
// All LDS except dwT/d2s is wave-private -> ONE __syncthreads total.
// Lane l owns fcat columns c0 = l (all lanes) and c1 = 64+l (lanes < 32).
//   fcat col 0..31  = lifted ; col 32..95 = gathered fts cols 0..63.
// ---------------------------------------------------------------------------
__global__ __launch_bounds__(256, 4) void final_stage_kernel(
    const float* __restrict__ X2,         // [32768][256]
    const float* __restrict__ pts_local,  // [32768][48] (k*3+d)
    const int* __restrict__ pts_idx,
    const float* __restrict__ fts_l,  // [16*8192][64]
    const float* __restrict__ d1_W, const float* __restrict__ d1_b,
    const float* __restrict__ d1_g, const float* __restrict__ d1_bt,
    const float* __restrict__ d2_W, const float* __restrict__ d2_b,
    const float* __restrict__ d2_g, const float* __restrict__ d2_bt,
    const float* __restrict__ dw_W, const float* __restrict__ dw_b,
    float* __restrict__ dw_out)  // [32768][192]
{
    __shared__ float X_s[4][256];      // wave-private
    __shared__ float l0_s[4][16][32];  // wave-private; l0 then lifted
    __shared__ float pl_s[4][48];      // wave-private
    __shared__ int idx_s[4][16];       // wave-private
    __shared__ float dwT[2][16][101];  // cooperative: dw_W[c][m][k] -> [m][k][c]
    __shared__ float d2s[32][33];      // cooperative: d2_W [q][c], padded

    const int tid = threadIdx.x;
    const int w = tid >> 6;   // wave = point within block
    const int l = tid & 63;   // lane
    const long gp = (long)blockIdx.x * 4 + w;
    const int n = (int)(gp >> 11);
    const int c32 = l & 31, h = l >> 5;

    // ---- wave-private staging (no barrier needed) ----
    *reinterpret_cast<float4*>(&X_s[w][l * 4]) =
        *reinterpret_cast<const float4*>(&X2[gp * 256 + l * 4]);
    if (l < 16) idx_s[w][l] = pts_idx[gp * 32 + 2 * l];
    if (l < 48) pl_s[w][l] = pts_local[gp * 48 + l];

    // ---- cooperative staging (needs the one barrier) ----
    // dw_W: 96*2*16 = 3072 elements = 12 * 256
#pragma unroll
    for (int i = 0; i < 12; ++i) {
        const int e = i * 256 + tid;  // e = c*32 + m*16 + k
        const int c = e >> 5, r = e & 31;
        dwT[r >> 4][r & 15][c] = dw_W[e];
    }
    // d2_W: 32*32 = 1024 = 4 * 256
#pragma unroll
    for (int i = 0; i < 4; ++i) {
        const int e = i * 256 + tid;  // e = q*32 + c
        d2s[e >> 5][e & 31] = d2_W[e];
    }
    __syncthreads();  // the only block-wide barrier

    // ---- issue fts gather; latency hides under l0 + lifted ----
    const int colg = (l < 32) ? (32 + l) : (l - 32);
    float fg[16];
    const float* fbase = fts_l + (long)n * 8192 * 64 + colg;
#pragma unroll
    for (int j = 0; j < 16; ++j) fg[j] = fbase[(long)idx_s[w][j] * 64];

    // ---- l0: lane (c32,h) computes rows h*8..h*8+7 of col c32 ----
    {
        const float w0 = d1_W[0 * 32 + c32], w1 = d1_W[1 * 32 + c32],
                    w2 = d1_W[2 * 32 + c32];
        const float b = d1_b[c32], gsc = d1_g[c32] * RS, bt = d1_bt[c32];
#pragma unroll
        for (int jl = 0; jl < 8; ++jl) {
            const int j = h * 8 + jl;
            float a = b;
            a = fmaf(pl_s[w][j * 3 + 0], w0, a);
            a = fmaf(pl_s[w][j * 3 + 1], w1, a);
            a = fmaf(pl_s[w][j * 3 + 2], w2, a);
            a = eluf(a);
            l0_s[w][j][c32] = a * gsc + bt;
        }
    }
    // wave-private RAW on l0_s: ordered by lgkmcnt within the wave.

    // ---- lifted: lane (c32,h) computes rows h*8..h*8+7 of col c32 ----
    float lf[8];
    {
        const float b = d2_b[c32];
#pragma unroll
        for (int jl = 0; jl < 8; ++jl) lf[jl] = b;
#pragma unroll
        for (int q4 = 0; q4 < 8; ++q4) {
            const float w0 = d2s[q4 * 4 + 0][c32];
            const float w1 = d2s[q4 * 4 + 1][c32];
            const float w2 = d2s[q4 * 4 + 2][c32];
            const float w3 = d2s[q4 * 4 + 3][c32];
#pragma unroll
            for (int jl = 0; jl < 8; ++jl) {
                const float4 lv = *reinterpret_cast<const float4*>(
                    &l0_s[w][h * 8 + jl][q4 * 4]);
                lf[jl] = fmaf(lv.x, w0, lf[jl]);
                lf[jl] = fmaf(lv.y, w1, lf[jl]);
                lf[jl] = fmaf(lv.z, w2, lf[jl]);
                lf[jl] = fmaf(lv.w, w3, lf[jl]);
            }
        }
        const float gsc = d2_g[c32] * RS, bt = d2_bt[c32];
#pragma unroll
        for (int jl = 0; jl < 8; ++jl) lf[jl] = eluf(lf[jl]) * gsc + bt;
    }
    // overwrite l0_s with lifted (same wave wrote+read it; in-order)
#pragma unroll
    for (int jl = 0; jl < 8; ++jl) l0_s[w][h * 8 + jl][c32] = lf[jl];

    // ---- fA[j]: lanes<32 -> lifted col l; lanes>=32 -> fg (fts col l-32) ----
    float fA[16];
#pragma unroll
    for (int j = 0; j < 16; ++j) {
        const float flv = l0_s[w][j][c32];
        fA[j] = (l < 32) ? flv : fg[j];
    }

    // ---- fts_X: accA[i] = sum_j X[i][j]*fA[j]; accB[i] = sum_j X[i][j]*fg[j]
    float accA[16], accB[16];
#pragma unroll
    for (int i = 0; i < 16; ++i) {
        accA[i] = 0.0f;
        accB[i] = 0.0f;
    }
#pragma unroll
    for (int i = 0; i < 16; ++i) {
#pragma unroll
        for (int j4 = 0; j4 < 4; ++j4) {
            const float4 xv =
                *reinterpret_cast<const float4*>(&X_s[w][i * 16 + j4 * 4]);
            accA[i] = fmaf(xv.x, fA[j4 * 4 + 0], accA[i]);
            accA[i] = fmaf(xv.y, fA[j4 * 4 + 1], accA[i]);
            accA[i] = fmaf(xv.z, fA[j4 * 4 + 2], accA[i]);
            accA[i] = fmaf(xv.w, fA[j4 * 4 + 3], accA[i]);
            accB[i] = fmaf(xv.x, fg[j4 * 4 + 0], accB[i]);
            accB[i] = fmaf(xv.y, fg[j4 * 4 + 1], accB[i]);
            accB[i] = fmaf(xv.z, fg[j4 * 4 + 2], accB[i]);
            accB[i] = fmaf(xv.w, fg[j4 * 4 + 3], accB[i]);
        }
    }

    // ---- dw: lane-local. col c0 = l (accA); col c1 = 64+l lanes<32 (accB) --
    {
        float o0 = dw_b[2 * l + 0], o1 = dw_b[2 * l + 1];
#pragma unroll
        for (int k = 0; k < 16; ++k) {
            o0 = fmaf(accA[k], dwT[0][k][l], o0);
            o1 = fmaf(accA[k], dwT[1][k][l], o1);
        }
        *reinterpret_cast<float2*>(&dw_out[gp * 192 + 2 * l]) =
            make_float2(o0, o1);
        if (l < 32) {
            const int c1 = 64 + l;
            float p0 = dw_b[2 * c1 + 0], p1 = dw_b[2 * c1 + 1];
#pragma unroll
            for (int k = 0; k < 16; ++k) {
                p0 = fmaf(accB[k], dwT[0][k][c1], p0);
                p1 = fmaf(accB[k], dwT[1][k][c1], p1);
            }
            *reinterpret_cast<float2*>(&dw_out[gp * 192 + 2 * c1]) =
                make_float2(p0, p1);
        }
    }
}

extern "C" void kernel_launch(void* const* d_in, const int* in_sizes, int n_in,
                              void* d_out, int out_size, void* d_ws,
                              size_t ws_size, hipStream_t stream) {
    const float* rep_pts = (const float*)d_in[0];
    const float* pts = (const float*)d_in[1];
    const float* fts = (const float*)d_in[2];
    const int* pts_idx = (const int*)d_in[3];
    const float* dense_W = (const float*)d_in[4];
    const float* dense_b = (const float*)d_in[5];
    const float* dense_g = (const float*)d_in[6];
    const float* dense_bt = (const float*)d_in[7];
    const float* d1_W = (const float*)d_in[8];
    const float* d1_b = (const float*)d_in[9];
    const float* d1_g = (const float*)d_in[10];
    const float* d1_bt = (const float*)d_in[11];
    const float* d2_W = (const float*)d_in[12];
    const float* d2_b = (const float*)d_in[13];
    const float* d2_g = (const float*)d_in[14];
    const float* d2_bt = (const float*)d_in[15];
    const float* xt_cW = (const float*)d_in[16];
    const float* xt_cb = (const float*)d_in[17];
    const float* xt_d1W = (const float*)d_in[18];
    const float* xt_d1b = (const float*)d_in[19];
    const float* xt_d2W = (const float*)d_in[20];
    const float* xt_d2b = (const float*)d_in[21];
    const float* dw_W = (const float*)d_in[22];
    const float* dw_b = (const float*)d_in[23];
    const float* pw_W = (const float*)d_in[24];
    const float* pw_b = (const float*)d_in[25];
    const float* sep_g = (const float*)d_in[26];
    const float* sep_bt = (const float*)d_in[27];

    float* ws = (float*)d_ws;
    float* fts_l = ws;               // 131072*64  = 8388608 f32
    float* bufA = ws + 8388608;      // Xc then X2 : 32768*256
    float* bufB = ws + 16777216;     // X1 then dw : 32768*256
    float* pl = ws + 25165824;       // 32768*48

    // 1) fts_l = bn(elu(fts @ dense_W + b))   (131072 x 64) @ (64 x 64)
    gemm_bias_act<1, 1><<<dim3(2048, 1), 256, 0, stream>>>(
        fts, dense_W, dense_b, dense_g, dense_bt, fts_l, 64, 64);

    // 2) pts_local + Xc
    setup_kernel<<<2048, 256, 0, stream>>>(rep_pts, pts, pts_idx, xt_cW, xt_cb,
                                           pl, bufA);

    // 3) X1 = elu(Xc @ xt_d1W + b)   (32768 x 256) @ (256 x 256)
    gemm_bias_act<1, 0><<<dim3(512, 4), 256, 0, stream>>>(
        bufA, xt_d1W, xt_d1b, nullptr, nullptr, bufB, 256, 256);

    // 4) X2 = X1 @ xt_d2W + b
    gemm_bias_act<0, 0><<<dim3(512, 4), 256, 0, stream>>>(
        bufB, xt_d2W, xt_d2b, nullptr, nullptr, bufA, 256, 256);

    // 5) lifted/gather/fts_X/dw -> bufB [32768][192]
    final_stage_kernel<<<8192, 256, 0, stream>>>(
        bufA, pl, pts_idx, fts_l, d1_W, d1_b, d1_g, d1_bt, d2_W, d2_b, d2_g,
        d2_bt, dw_W, dw_b, bufB);

    // 6) out = bn(elu(dw @ pw_W + pw_b))   (32768 x 192) @ (192 x 128)
    gemm_bias_act<1, 1><<<dim3(512, 2), 256, 0, stream>>>(
        bufB, pw_W, pw_b, sep_g, sep_bt, (float*)d_out, 192, 128);
}

// Round 5
// 403.676 us; speedup vs baseline: 1.6386x; 1.6386x over previous
//
#include <hip/hip_runtime.h>
#include <hip/hip_bf16.h>

#define RS 0.9999950000374998f  // 1/sqrt(1+1e-5)

__device__ __forceinline__ float eluf(float x) {
    return x > 0.0f ? x : expf(x) - 1.0f;
}

// ---------------------------------------------------------------------------
// Generic tiled f32 GEMM: out[r, c] = post(sum_k A[r,k] * W[k,c] + bias[c])
// post: ACT -> elu; BN -> *gamma/sqrt(1+eps) + beta
// rows multiple of 64, Ncols multiple of 64, Kdim multiple of 16.
// block 256, grid (rows/64, Ncols/64)
// ---------------------------------------------------------------------------
template <int ACT, int BN>
__global__ __launch_bounds__(256) void gemm_bias_act(
    const float* __restrict__ A, const float* __restrict__ W,
    const float* __restrict__ bias, const float* __restrict__ gamma,
    const float* __restrict__ beta, float* __restrict__ out,
    int Kdim, int Ncols) {
    __shared__ float As[16][64];
    __shared__ float Bs[16][64];
    const int tid = threadIdx.x;
    const int tx = tid & 15, ty = tid >> 4;
    const long row0 = (long)blockIdx.x * 64;
    const int col0 = blockIdx.y * 64;
    const int rA = tid >> 2, kqA = (tid & 3) << 2;
    const int kkB = tid >> 4, cqB = (tid & 15) << 2;
    float acc[4][4] = {};
    for (int k0 = 0; k0 < Kdim; k0 += 16) {
        const float4 av = *reinterpret_cast<const float4*>(
            A + (row0 + rA) * (long)Kdim + (k0 + kqA));
        const float4 bv = *reinterpret_cast<const float4*>(
            W + (long)(k0 + kkB) * Ncols + (col0 + cqB));
        As[kqA + 0][rA] = av.x;
        As[kqA + 1][rA] = av.y;
        As[kqA + 2][rA] = av.z;
        As[kqA + 3][rA] = av.w;
        *reinterpret_cast<float4*>(&Bs[kkB][cqB]) = bv;
        __syncthreads();
#pragma unroll
        for (int kk = 0; kk < 16; ++kk) {
            float a[4], b[4];
#pragma unroll
            for (int i = 0; i < 4; ++i) a[i] = As[kk][ty * 4 + i];
#pragma unroll
            for (int j = 0; j < 4; ++j) b[j] = Bs[kk][tx * 4 + j];
#pragma unroll
            for (int i = 0; i < 4; ++i)
#pragma unroll
                for (int j = 0; j < 4; ++j) acc[i][j] = fmaf(a[i], b[j], acc[i][j]);
        }
        __syncthreads();
    }
#pragma unroll
    for (int j = 0; j < 4; ++j) {
        const int col = col0 + tx * 4 + j;
        const float bb = bias[col];
        const float gs = BN ? gamma[col] * RS : 0.0f;
        const float bt = BN ? beta[col] : 0.0f;
#pragma unroll
        for (int i = 0; i < 4; ++i) {
            const long row = row0 + ty * 4 + i;
            float v = acc[i][j] + bb;
            if (ACT) v = eluf(v);
            if (BN) v = v * gs + bt;
            out[row * Ncols + col] = v;
        }
    }
}

// ---------------------------------------------------------------------------
// Setup: per point, gather neighbor coords, compute pts_local (store) and
// Xc[gp, o] = elu(sum_{d,k} pts_local[k,d] * xt_cW[o,d,k] + cb[o])  (store)
// 16 points per block, 256 threads. grid = 32768/16 = 2048.
// ---------------------------------------------------------------------------
__global__ __launch_bounds__(256) void setup_kernel(
    const float* __restrict__ rep_pts, const float* __restrict__ pts,
    const int* __restrict__ pts_idx, const float* __restrict__ xt_cW,
    const float* __restrict__ xt_cb, float* __restrict__ pts_local,
    float* __restrict__ Xc) {
    __shared__ float cwT[48][256];  // cwT[d*16+k][o] = xt_cW[o,d,k]
    __shared__ float pl2[16][48];   // pl2[pt][d*16+k]
    __shared__ float cb_s[256];
    const int tid = threadIdx.x;
    const long gp0 = (long)blockIdx.x * 16;
#pragma unroll
    for (int i = 0; i < 48; ++i) cwT[i][tid] = xt_cW[tid * 48 + i];
    cb_s[tid] = xt_cb[tid];
    {
        const int pt = tid >> 4, k = tid & 15;
        const long gp = gp0 + pt;
        const int n = (int)(gp >> 11);
        const int idx = pts_idx[gp * 32 + 2 * k];
        const float* ps = pts + ((long)n * 8192 + idx) * 3;
        const float* rs = rep_pts + gp * 3;
        float* plo = pts_local + gp * 48 + k * 3;
#pragma unroll
        for (int d = 0; d < 3; ++d) {
            const float v = ps[d] - rs[d];
            pl2[pt][d * 16 + k] = v;
            plo[d] = v;
        }
    }
    __syncthreads();
    const int o = tid;
    for (int pt = 0; pt < 16; ++pt) {
        float acc = cb_s[o];
#pragma unroll
        for (int i = 0; i < 48; ++i) acc = fmaf(pl2[pt][i], cwT[i][o], acc);
        Xc[(gp0 + pt) * 256 + o] = eluf(acc);
    }
}

// ---------------------------------------------------------------------------
// Final per-point stage, wave-per-point column-owner layout, v4.
// Block = 256 threads = 4 waves = 4 points. grid = 32768/4 = 8192.
// All LDS except dwT/d2s is wave-private -> ONE __syncthreads total.
// NOTE: no second __launch_bounds__ arg — (256,4) made LLVM clamp to 64 VGPR
// and spill ~1.4 GB of scratch (R4 post-mortem). Plain 256 lets the
// allocator pick ~120 VGPR with zero spill.
// Lane l owns fcat columns c0 = l (all lanes) and c1 = 64+l (lanes < 32).
//   fcat col 0..31  = lifted ; col 32..95 = gathered fts cols 0..63.
// ---------------------------------------------------------------------------
__global__ __launch_bounds__(256) void final_stage_kernel(
    const float* __restrict__ X2,         // [32768][256]
    const float* __restrict__ pts_local,  // [32768][48] (k*3+d)
    const int* __restrict__ pts_idx,
    const float* __restrict__ fts_l,  // [16*8192][64]
    const float* __restrict__ d1_W, const float* __restrict__ d1_b,
    const float* __restrict__ d1_g, const float* __restrict__ d1_bt,
    const float* __restrict__ d2_W, const float* __restrict__ d2_b,
    const float* __restrict__ d2_g, const float* __restrict__ d2_bt,
    const float* __restrict__ dw_W, const float* __restrict__ dw_b,
    float* __restrict__ dw_out)  // [32768][192]
{
    __shared__ float X_s[4][256];      // wave-private
    __shared__ float l0_s[4][16][32];  // wave-private; l0 then lifted
    __shared__ float pl_s[4][48];      // wave-private
    __shared__ int idx_s[4][16];       // wave-private
    __shared__ float dwT[2][16][101];  // cooperative: dw_W[c][m][k] -> [m][k][c]
    __shared__ float d2s[32][33];      // cooperative: d2_W [q][c], padded

    const int tid = threadIdx.x;
    const int w = tid >> 6;   // wave = point within block
    const int l = tid & 63;   // lane
    const long gp = (long)blockIdx.x * 4 + w;
    const int n = (int)(gp >> 11);
    const int c32 = l & 31, h = l >> 5;

    // ---- wave-private staging (no barrier needed) ----
    *reinterpret_cast<float4*>(&X_s[w][l * 4]) =
        *reinterpret_cast<const float4*>(&X2[gp * 256 + l * 4]);
    if (l < 16) idx_s[w][l] = pts_idx[gp * 32 + 2 * l];
    if (l < 48) pl_s[w][l] = pts_local[gp * 48 + l];

    // ---- cooperative staging (needs the one barrier) ----
    // dw_W: 96*2*16 = 3072 elements = 12 * 256
#pragma unroll
    for (int i = 0; i < 12; ++i) {
        const int e = i * 256 + tid;  // e = c*32 + m*16 + k
        const int c = e >> 5, r = e & 31;
        dwT[r >> 4][r & 15][c] = dw_W[e];
    }
    // d2_W: 32*32 = 1024 = 4 * 256
#pragma unroll
    for (int i = 0; i < 4; ++i) {
        const int e = i * 256 + tid;  // e = q*32 + c
        d2s[e >> 5][e & 31] = d2_W[e];
    }
    __syncthreads();  // the only block-wide barrier

    // ---- issue fts gather; latency hides under l0 + lifted ----
    const int colg = (l < 32) ? (32 + l) : (l - 32);
    float fg[16];
    const float* fbase = fts_l + (long)n * 8192 * 64 + colg;
#pragma unroll
    for (int j = 0; j < 16; ++j) fg[j] = fbase[(long)idx_s[w][j] * 64];

    // ---- l0: lane (c32,h) computes rows h*8..h*8+7 of col c32 ----
    {
        const float w0 = d1_W[0 * 32 + c32], w1 = d1_W[1 * 32 + c32],
                    w2 = d1_W[2 * 32 + c32];
        const float b = d1_b[c32], gsc = d1_g[c32] * RS, bt = d1_bt[c32];
#pragma unroll
        for (int jl = 0; jl < 8; ++jl) {
            const int j = h * 8 + jl;
            float a = b;
            a = fmaf(pl_s[w][j * 3 + 0], w0, a);
            a = fmaf(pl_s[w][j * 3 + 1], w1, a);
            a = fmaf(pl_s[w][j * 3 + 2], w2, a);
            a = eluf(a);
            l0_s[w][j][c32] = a * gsc + bt;
        }
    }
    // wave-private RAW on l0_s: ordered by lgkmcnt within the wave.

    // ---- lifted: lane (c32,h) computes rows h*8..h*8+7 of col c32 ----
    float lf[8];
    {
        const float b = d2_b[c32];
#pragma unroll
        for (int jl = 0; jl < 8; ++jl) lf[jl] = b;
#pragma unroll
        for (int q4 = 0; q4 < 8; ++q4) {
            const float w0 = d2s[q4 * 4 + 0][c32];
            const float w1 = d2s[q4 * 4 + 1][c32];
            const float w2 = d2s[q4 * 4 + 2][c32];
            const float w3 = d2s[q4 * 4 + 3][c32];
#pragma unroll
            for (int jl = 0; jl < 8; ++jl) {
                const float4 lv = *reinterpret_cast<const float4*>(
                    &l0_s[w][h * 8 + jl][q4 * 4]);
                lf[jl] = fmaf(lv.x, w0, lf[jl]);
                lf[jl] = fmaf(lv.y, w1, lf[jl]);
                lf[jl] = fmaf(lv.z, w2, lf[jl]);
                lf[jl] = fmaf(lv.w, w3, lf[jl]);
            }
        }
        const float gsc = d2_g[c32] * RS, bt = d2_bt[c32];
#pragma unroll
        for (int jl = 0; jl < 8; ++jl) lf[jl] = eluf(lf[jl]) * gsc + bt;
    }
    // overwrite l0_s with lifted (same wave wrote+read it; in-order)
#pragma unroll
    for (int jl = 0; jl < 8; ++jl) l0_s[w][h * 8 + jl][c32] = lf[jl];

    // ---- fA[j]: lanes<32 -> lifted col l; lanes>=32 -> fg (fts col l-32) ----
    float fA[16];
#pragma unroll
    for (int j = 0; j < 16; ++j) {
        const float flv = l0_s[w][j][c32];
        fA[j] = (l < 32) ? flv : fg[j];
    }

    // ---- fts_X: accA[i] = sum_j X[i][j]*fA[j]; accB[i] = sum_j X[i][j]*fg[j]
    float accA[16], accB[16];
#pragma unroll
    for (int i = 0; i < 16; ++i) {
        accA[i] = 0.0f;
        accB[i] = 0.0f;
    }
#pragma unroll
    for (int i = 0; i < 16; ++i) {
#pragma unroll
        for (int j4 = 0; j4 < 4; ++j4) {
            const float4 xv =
                *reinterpret_cast<const float4*>(&X_s[w][i * 16 + j4 * 4]);
            accA[i] = fmaf(xv.x, fA[j4 * 4 + 0], accA[i]);
            accA[i] = fmaf(xv.y, fA[j4 * 4 + 1], accA[i]);
            accA[i] = fmaf(xv.z, fA[j4 * 4 + 2], accA[i]);
            accA[i] = fmaf(xv.w, fA[j4 * 4 + 3], accA[i]);
            accB[i] = fmaf(xv.x, fg[j4 * 4 + 0], accB[i]);
            accB[i] = fmaf(xv.y, fg[j4 * 4 + 1], accB[i]);
            accB[i] = fmaf(xv.z, fg[j4 * 4 + 2], accB[i]);
            accB[i] = fmaf(xv.w, fg[j4 * 4 + 3], accB[i]);
        }
    }

    // ---- dw: lane-local. col c0 = l (accA); col c1 = 64+l lanes<32 (accB) --
    {
        float o0 = dw_b[2 * l + 0], o1 = dw_b[2 * l + 1];
#pragma unroll
        for (int k = 0; k < 16; ++k) {
            o0 = fmaf(accA[k], dwT[0][k][l], o0);
            o1 = fmaf(accA[k], dwT[1][k][l], o1);
        }
        *reinterpret_cast<float2*>(&dw_out[gp * 192 + 2 * l]) =
            make_float2(o0, o1);
        if (l < 32) {
            const int c1 = 64 + l;
            float p0 = dw_b[2 * c1 + 0], p1 = dw_b[2 * c1 + 1];
#pragma unroll
            for (int k = 0; k < 16; ++k) {
                p0 = fmaf(accB[k], dwT[0][k][c1], p0);
                p1 = fmaf(accB[k], dwT[1][k][c1], p1);
            }
            *reinterpret_cast<float2*>(&dw_out[gp * 192 + 2 * c1]) =
                make_float2(p0, p1);
        }
    }
}

extern "C" void kernel_launch(void* const* d_in, const int* in_sizes, int n_in,
                              void* d_out, int out_size, void* d_ws,
                              size_t ws_size, hipStream_t stream) {
    const float* rep_pts = (const float*)d_in[0];
    const float* pts = (const float*)d_in[1];
    const float* fts = (const float*)d_in[2];
    const int* pts_idx = (const int*)d_in[3];
    const float* dense_W = (const float*)d_in[4];
    const float* dense_b = (const float*)d_in[5];
    const float* dense_g = (const float*)d_in[6];
    const float* dense_bt = (const float*)d_in[7];
    const float* d1_W = (const float*)d_in[8];
    const float* d1_b = (const float*)d_in[9];
    const float* d1_g = (const float*)d_in[10];
    const float* d1_bt = (const float*)d_in[11];
    const float* d2_W = (const float*)d_in[12];
    const float* d2_b = (const float*)d_in[13];
    const float* d2_g = (const float*)d_in[14];
    const float* d2_bt = (const float*)d_in[15];
    const float* xt_cW = (const float*)d_in[16];
    const float* xt_cb = (const float*)d_in[17];
    const float* xt_d1W = (const float*)d_in[18];
    const float* xt_d1b = (const float*)d_in[19];
    const float* xt_d2W = (const float*)d_in[20];
    const float* xt_d2b = (const float*)d_in[21];
    const float* dw_W = (const float*)d_in[22];
    const float* dw_b = (const float*)d_in[23];
    const float* pw_W = (const float*)d_in[24];
    const float* pw_b = (const float*)d_in[25];
    const float* sep_g = (const float*)d_in[26];
    const float* sep_bt = (const float*)d_in[27];

    float* ws = (float*)d_ws;
    float* fts_l = ws;               // 131072*64  = 8388608 f32
    float* bufA = ws + 8388608;      // Xc then X2 : 32768*256
    float* bufB = ws + 16777216;     // X1 then dw : 32768*256
    float* pl = ws + 25165824;       // 32768*48

    // 1) fts_l = bn(elu(fts @ dense_W + b))   (131072 x 64) @ (64 x 64)
    gemm_bias_act<1, 1><<<dim3(2048, 1), 256, 0, stream>>>(
        fts, dense_W, dense_b, dense_g, dense_bt, fts_l, 64, 64);

    // 2) pts_local + Xc
    setup_kernel<<<2048, 256, 0, stream>>>(rep_pts, pts, pts_idx, xt_cW, xt_cb,
                                           pl, bufA);

    // 3) X1 = elu(Xc @ xt_d1W + b)   (32768 x 256) @ (256 x 256)
    gemm_bias_act<1, 0><<<dim3(512, 4), 256, 0, stream>>>(
        bufA, xt_d1W, xt_d1b, nullptr, nullptr, bufB, 256, 256);

    // 4) X2 = X1 @ xt_d2W + b
    gemm_bias_act<0, 0><<<dim3(512, 4), 256, 0, stream>>>(
        bufB, xt_d2W, xt_d2b, nullptr, nullptr, bufA, 256, 256);

    // 5) lifted/gather/fts_X/dw -> bufB [32768][192]
    final_stage_kernel<<<8192, 256, 0, stream>>>(
        bufA, pl, pts_idx, fts_l, d1_W, d1_b, d1_g, d1_bt, d2_W, d2_b, d2_g,
        d2_bt, dw_W, dw_b, bufB);

    // 6) out = bn(elu(dw @ pw_W + pw_b))   (32768 x 192) @ (192 x 128)
    gemm_bias_act<1, 1><<<dim3(512, 2), 256, 0, stream>>>(
        bufB, pw_W, pw_b, sep_g, sep_bt, (float*)d_out, 192, 128);
}

// Round 6
// 329.456 us; speedup vs baseline: 2.0077x; 1.2253x over previous
//
#include <hip/hip_runtime.h>
#include <hip/hip_bf16.h>

#define RS 0.9999950000374998f  // 1/sqrt(1+1e-5)

__device__ __forceinline__ float eluf(float x) {
    return x > 0.0f ? x : __expf(x) - 1.0f;
}

// ---------------------------------------------------------------------------
// Generic tiled f32 GEMM: out[r, c] = post(sum_k A[r,k] * W[k,c] + bias[c])
// post: ACT -> elu; BN -> *gamma/sqrt(1+eps) + beta
// rows multiple of 64, Ncols multiple of 64, Kdim multiple of 16.
// block 256, grid (rows/64, Ncols/64)
// ---------------------------------------------------------------------------
template <int ACT, int BN>
__global__ __launch_bounds__(256) void gemm_bias_act(
    const float* __restrict__ A, const float* __restrict__ W,
    const float* __restrict__ bias, const float* __restrict__ gamma,
    const float* __restrict__ beta, float* __restrict__ out,
    int Kdim, int Ncols) {
    __shared__ float As[16][64];
    __shared__ float Bs[16][64];
    const int tid = threadIdx.x;
    const int tx = tid & 15, ty = tid >> 4;
    const long row0 = (long)blockIdx.x * 64;
    const int col0 = blockIdx.y * 64;
    const int rA = tid >> 2, kqA = (tid & 3) << 2;
    const int kkB = tid >> 4, cqB = (tid & 15) << 2;
    float acc[4][4] = {};
    for (int k0 = 0; k0 < Kdim; k0 += 16) {
        const float4 av = *reinterpret_cast<const float4*>(
            A + (row0 + rA) * (long)Kdim + (k0 + kqA));
        const float4 bv = *reinterpret_cast<const float4*>(
            W + (long)(k0 + kkB) * Ncols + (col0 + cqB));
        As[kqA + 0][rA] = av.x;
        As[kqA + 1][rA] = av.y;
        As[kqA + 2][rA] = av.z;
        As[kqA + 3][rA] = av.w;
        *reinterpret_cast<float4*>(&Bs[kkB][cqB]) = bv;
        __syncthreads();
#pragma unroll
        for (int kk = 0; kk < 16; ++kk) {
            float a[4], b[4];
#pragma unroll
            for (int i = 0; i < 4; ++i) a[i] = As[kk][ty * 4 + i];
#pragma unroll
            for (int j = 0; j < 4; ++j) b[j] = Bs[kk][tx * 4 + j];
#pragma unroll
            for (int i = 0; i < 4; ++i)
#pragma unroll
                for (int j = 0; j < 4; ++j) acc[i][j] = fmaf(a[i], b[j], acc[i][j]);
        }
        __syncthreads();
    }
#pragma unroll
    for (int j = 0; j < 4; ++j) {
        const int col = col0 + tx * 4 + j;
        const float bb = bias[col];
        const float gs = BN ? gamma[col] * RS : 0.0f;
        const float bt = BN ? beta[col] : 0.0f;
#pragma unroll
        for (int i = 0; i < 4; ++i) {
            const long row = row0 + ty * 4 + i;
            float v = acc[i][j] + bb;
            if (ACT) v = eluf(v);
            if (BN) v = v * gs + bt;
            out[row * Ncols + col] = v;
        }
    }
}

// ---------------------------------------------------------------------------
// Setup: per point, gather neighbor coords, compute pts_local (store) and
// Xc[gp, o] = elu(sum_{d,k} pts_local[k,d] * xt_cW[o,d,k] + cb[o])  (store)
// 16 points per block, 256 threads. grid = 32768/16 = 2048.
// ---------------------------------------------------------------------------
__global__ __launch_bounds__(256) void setup_kernel(
    const float* __restrict__ rep_pts, const float* __restrict__ pts,
    const int* __restrict__ pts_idx, const float* __restrict__ xt_cW,
    const float* __restrict__ xt_cb, float* __restrict__ pts_local,
    float* __restrict__ Xc) {
    __shared__ float cwT[48][256];  // cwT[d*16+k][o] = xt_cW[o,d,k]
    __shared__ float pl2[16][48];   // pl2[pt][d*16+k]
    __shared__ float cb_s[256];
    const int tid = threadIdx.x;
    const long gp0 = (long)blockIdx.x * 16;
    // coalesced staging: e runs linearly over xt_cW (12288 = 48*256)
#pragma unroll
    for (int i = 0; i < 48; ++i) {
        const int e = i * 256 + tid;
        const int o = e / 48, r = e - o * 48;
        cwT[r][o] = xt_cW[e];
    }
    cb_s[tid] = xt_cb[tid];
    {
        const int pt = tid >> 4, k = tid & 15;
        const long gp = gp0 + pt;
        const int n = (int)(gp >> 11);
        const int idx = pts_idx[gp * 32 + 2 * k];
        const float* ps = pts + ((long)n * 8192 + idx) * 3;
        const float* rs = rep_pts + gp * 3;
        float* plo = pts_local + gp * 48 + k * 3;
#pragma unroll
        for (int d = 0; d < 3; ++d) {
            const float v = ps[d] - rs[d];
            pl2[pt][d * 16 + k] = v;
            plo[d] = v;
        }
    }
    __syncthreads();
    const int o = tid;
    for (int pt = 0; pt < 16; ++pt) {
        float acc = cb_s[o];
#pragma unroll
        for (int i = 0; i < 48; ++i) acc = fmaf(pl2[pt][i], cwT[i][o], acc);
        Xc[(gp0 + pt) * 256 + o] = eluf(acc);
    }
}

// ---------------------------------------------------------------------------
// Final per-point stage v5: wave-per-point, column-owner, SGPR-scalarized.
// Block = 256 threads = 4 waves = 4 points. grid = 32768/4 = 8192.
// Wave-uniform data (X row, pts_idx row) is read through a
// readfirstlane-uniform pointer -> s_load; SGPR operands feed v_fma directly.
// dw_W read directly from global (L2-resident, lane-local float4 column).
// lifted's upper 8 rows cross lanes via one __shfl_xor(32) (no LDS rt).
// NOTE: no 2nd __launch_bounds__ arg — (256,4) clamped to 64 VGPR and spilled
// 1.4 GB scratch (R4 post-mortem).
// ---------------------------------------------------------------------------
__global__ __launch_bounds__(256) void final_stage_kernel(
    const float* __restrict__ X2,         // [32768][256]
    const float* __restrict__ pts_local,  // [32768][48] (k*3+d)
    const int* __restrict__ pts_idx,
    const float* __restrict__ fts_l,  // [16*8192][64]
    const float* __restrict__ d1_W, const float* __restrict__ d1_b,
    const float* __restrict__ d1_g, const float* __restrict__ d1_bt,
    const float* __restrict__ d2_W, const float* __restrict__ d2_b,
    const float* __restrict__ d2_g, const float* __restrict__ d2_bt,
    const float* __restrict__ dw_W, const float* __restrict__ dw_b,
    float* __restrict__ dw_out)  // [32768][192]
{
    __shared__ float l0_s[4][16][32];  // wave-private l0
    __shared__ float pl_s[4][48];      // wave-private
    __shared__ float d2s[32][33];      // cooperative: d2_W [q][c], padded

    const int tid = threadIdx.x;
    const int w = tid >> 6;   // wave = point within block
    const int l = tid & 63;   // lane
    const int gp = blockIdx.x * 4 + w;
    const int ugp = __builtin_amdgcn_readfirstlane(gp);  // wave-uniform
    const int n = ugp >> 11;
    const int c32 = l & 31, h = l >> 5;

    // ---- wave-private / uniform staging ----
    if (l < 48) pl_s[w][l] = pts_local[(long)ugp * 48 + l];

    // ---- cooperative d2_W staging (the only barrier) ----
#pragma unroll
    for (int i = 0; i < 4; ++i) {
        const int e = i * 256 + tid;  // e = q*32 + c
        d2s[e >> 5][e & 31] = d2_W[e];
    }
    __syncthreads();

    // ---- fts gather (issued early; consumed at fts_X) ----
    // idx through uniform pointer -> s_load; address = sgpr_idx*256B + colg*4
    const int* __restrict__ ip = pts_idx + (long)ugp * 32;
    const int colg = (l < 32) ? (32 + l) : (l - 32);
    const float* __restrict__ fbase = fts_l + (long)n * 8192 * 64 + colg;
    float fg[16];
#pragma unroll
    for (int j = 0; j < 16; ++j) fg[j] = fbase[(long)ip[2 * j] * 64];

    // ---- l0: lane (c32,h) computes rows h*8..h*8+7 of col c32 ----
    {
        const float w0 = d1_W[0 * 32 + c32], w1 = d1_W[1 * 32 + c32],
                    w2 = d1_W[2 * 32 + c32];
        const float b = d1_b[c32], gsc = d1_g[c32] * RS, bt = d1_bt[c32];
#pragma unroll
        for (int jl = 0; jl < 8; ++jl) {
            const int j = h * 8 + jl;
            float a = b;
            a = fmaf(pl_s[w][j * 3 + 0], w0, a);
            a = fmaf(pl_s[w][j * 3 + 1], w1, a);
            a = fmaf(pl_s[w][j * 3 + 2], w2, a);
            a = eluf(a);
            l0_s[w][j][c32] = a * gsc + bt;
        }
    }
    // wave-private RAW on l0_s: ordered by lgkmcnt within the wave.

    // ---- lifted: lane (c32,h) computes rows h*8..h*8+7 of col c32 ----
    float lf[8];
    {
        const float b = d2_b[c32];
#pragma unroll
        for (int jl = 0; jl < 8; ++jl) lf[jl] = b;
#pragma unroll
        for (int q4 = 0; q4 < 8; ++q4) {
            const float w0 = d2s[q4 * 4 + 0][c32];
            const float w1 = d2s[q4 * 4 + 1][c32];
            const float w2 = d2s[q4 * 4 + 2][c32];
            const float w3 = d2s[q4 * 4 + 3][c32];
#pragma unroll
            for (int jl = 0; jl < 8; ++jl) {
                const float4 lv = *reinterpret_cast<const float4*>(
                    &l0_s[w][h * 8 + jl][q4 * 4]);
                lf[jl] = fmaf(lv.x, w0, lf[jl]);
                lf[jl] = fmaf(lv.y, w1, lf[jl]);
                lf[jl] = fmaf(lv.z, w2, lf[jl]);
                lf[jl] = fmaf(lv.w, w3, lf[jl]);
            }
        }
        const float gsc = d2_g[c32] * RS, bt = d2_bt[c32];
#pragma unroll
        for (int jl = 0; jl < 8; ++jl) lf[jl] = eluf(lf[jl]) * gsc + bt;
    }

    // ---- fA: lanes<32 take lifted col l (rows 8..15 from lane l+32 via
    //      shfl_xor(32)); lanes>=32 take fg (fts col l-32) ----
    float fA[16];
#pragma unroll
    for (int j = 0; j < 8; ++j) {
        const float other = __shfl_xor(lf[j], 32);
        fA[j] = (l < 32) ? lf[j] : fg[j];
        fA[j + 8] = (l < 32) ? other : fg[j + 8];
    }

    // ---- fts_X: X row via uniform pointer (s_load -> SGPR fma operand) ----
    const float* __restrict__ Xu = X2 + (long)ugp * 256;
    float accA[16], accB[16];
#pragma unroll
    for (int i = 0; i < 16; ++i) {
        accA[i] = 0.0f;
        accB[i] = 0.0f;
    }
#pragma unroll
    for (int i = 0; i < 16; ++i) {
#pragma unroll
        for (int j = 0; j < 16; ++j) {
            const float xs = Xu[i * 16 + j];
            accA[i] = fmaf(xs, fA[j], accA[i]);
            accB[i] = fmaf(xs, fg[j], accB[i]);
        }
    }

    // ---- dw: lane-local; dw_W column read directly (coalesced float4) ----
    {
        float o0 = dw_b[2 * l + 0], o1 = dw_b[2 * l + 1];
        const float4* __restrict__ wp0 =
            reinterpret_cast<const float4*>(dw_W + l * 32);       // m=0,k0..15
        const float4* __restrict__ wp1 =
            reinterpret_cast<const float4*>(dw_W + l * 32 + 16);  // m=1
#pragma unroll
        for (int q = 0; q < 4; ++q) {
            const float4 w0 = wp0[q], w1 = wp1[q];
            o0 = fmaf(accA[q * 4 + 0], w0.x, o0);
            o0 = fmaf(accA[q * 4 + 1], w0.y, o0);
            o0 = fmaf(accA[q * 4 + 2], w0.z, o0);
            o0 = fmaf(accA[q * 4 + 3], w0.w, o0);
            o1 = fmaf(accA[q * 4 + 0], w1.x, o1);
            o1 = fmaf(accA[q * 4 + 1], w1.y, o1);
            o1 = fmaf(accA[q * 4 + 2], w1.z, o1);
            o1 = fmaf(accA[q * 4 + 3], w1.w, o1);
        }
        *reinterpret_cast<float2*>(&dw_out[(long)gp * 192 + 2 * l]) =
            make_float2(o0, o1);
        if (l < 32) {
            const int c1 = 64 + l;
            float p0 = dw_b[2 * c1 + 0], p1 = dw_b[2 * c1 + 1];
            const float4* __restrict__ vp0 =
                reinterpret_cast<const float4*>(dw_W + c1 * 32);
            const float4* __restrict__ vp1 =
                reinterpret_cast<const float4*>(dw_W + c1 * 32 + 16);
#pragma unroll
            for (int q = 0; q < 4; ++q) {
                const float4 w0 = vp0[q], w1 = vp1[q];
                p0 = fmaf(accB[q * 4 + 0], w0.x, p0);
                p0 = fmaf(accB[q * 4 + 1], w0.y, p0);
                p0 = fmaf(accB[q * 4 + 2], w0.z, p0);
                p0 = fmaf(accB[q * 4 + 3], w0.w, p0);
                p1 = fmaf(accB[q * 4 + 0], w1.x, p1);
                p1 = fmaf(accB[q * 4 + 1], w1.y, p1);
                p1 = fmaf(accB[q * 4 + 2], w1.z, p1);
                p1 = fmaf(accB[q * 4 + 3], w1.w, p1);
            }
            *reinterpret_cast<float2*>(&dw_out[(long)gp * 192 + 2 * c1]) =
                make_float2(p0, p1);
        }
    }
}

extern "C" void kernel_launch(void* const* d_in, const int* in_sizes, int n_in,
                              void* d_out, int out_size, void* d_ws,
                              size_t ws_size, hipStream_t stream) {
    const float* rep_pts = (const float*)d_in[0];
    const float* pts = (const float*)d_in[1];
    const float* fts = (const float*)d_in[2];
    const int* pts_idx = (const int*)d_in[3];
    const float* dense_W = (const float*)d_in[4];
    const float* dense_b = (const float*)d_in[5];
    const float* dense_g = (const float*)d_in[6];
    const float* dense_bt = (const float*)d_in[7];
    const float* d1_W = (const float*)d_in[8];
    const float* d1_b = (const float*)d_in[9];
    const float* d1_g = (const float*)d_in[10];
    const float* d1_bt = (const float*)d_in[11];
    const float* d2_W = (const float*)d_in[12];
    const float* d2_b = (const float*)d_in[13];
    const float* d2_g = (const float*)d_in[14];
    const float* d2_bt = (const float*)d_in[15];
    const float* xt_cW = (const float*)d_in[16];
    const float* xt_cb = (const float*)d_in[17];
    const float* xt_d1W = (const float*)d_in[18];
    const float* xt_d1b = (const float*)d_in[19];
    const float* xt_d2W = (const float*)d_in[20];
    const float* xt_d2b = (const float*)d_in[21];
    const float* dw_W = (const float*)d_in[22];
    const float* dw_b = (const float*)d_in[23];
    const float* pw_W = (const float*)d_in[24];
    const float* pw_b = (const float*)d_in[25];
    const float* sep_g = (const float*)d_in[26];
    const float* sep_bt = (const float*)d_in[27];

    float* ws = (float*)d_ws;
    float* fts_l = ws;               // 131072*64  = 8388608 f32
    float* bufA = ws + 8388608;      // Xc then X2 : 32768*256
    float* bufB = ws + 16777216;     // X1 then dw : 32768*256
    float* pl = ws + 25165824;       // 32768*48

    // 1) fts_l = bn(elu(fts @ dense_W + b))   (131072 x 64) @ (64 x 64)
    gemm_bias_act<1, 1><<<dim3(2048, 1), 256, 0, stream>>>(
        fts, dense_W, dense_b, dense_g, dense_bt, fts_l, 64, 64);

    // 2) pts_local + Xc
    setup_kernel<<<2048, 256, 0, stream>>>(rep_pts, pts, pts_idx, xt_cW, xt_cb,
                                           pl, bufA);

    // 3) X1 = elu(Xc @ xt_d1W + b)   (32768 x 256) @ (256 x 256)
    gemm_bias_act<1, 0><<<dim3(512, 4), 256, 0, stream>>>(
        bufA, xt_d1W, xt_d1b, nullptr, nullptr, bufB, 256, 256);

    // 4) X2 = X1 @ xt_d2W + b
    gemm_bias_act<0, 0><<<dim3(512, 4), 256, 0, stream>>>(
        bufB, xt_d2W, xt_d2b, nullptr, nullptr, bufA, 256, 256);

    // 5) lifted/gather/fts_X/dw -> bufB [32768][192]
    final_stage_kernel<<<8192, 256, 0, stream>>>(
        bufA, pl, pts_idx, fts_l, d1_W, d1_b, d1_g, d1_bt, d2_W, d2_b, d2_g,
        d2_bt, dw_W, dw_b, bufB);

    // 6) out = bn(elu(dw @ pw_W + pw_b))   (32768 x 192) @ (192 x 128)
    gemm_bias_act<1, 1><<<dim3(512, 2), 256, 0, stream>>>(
        bufB, pw_W, pw_b, sep_g, sep_bt, (float*)d_out, 192, 128);
}

// Round 7
// 220.266 us; speedup vs baseline: 3.0029x; 1.4957x over previous
//
#include <hip/hip_runtime.h>
#include <hip/hip_bf16.h>

#define RS 0.9999950000374998f  // 1/sqrt(1+1e-5)

__device__ __forceinline__ float eluf(float x) {
    return x > 0.0f ? x : __expf(x) - 1.0f;
}

typedef __attribute__((ext_vector_type(8))) __bf16 bf16x8;
typedef __attribute__((ext_vector_type(4))) float f32x4;

// ---------------------------------------------------------------------------
// f32 tiled GEMM (kept for fts_l whose input is f32).
// ---------------------------------------------------------------------------
template <int ACT, int BN>
__global__ __launch_bounds__(256) void gemm_bias_act(
    const float* __restrict__ A, const float* __restrict__ W,
    const float* __restrict__ bias, const float* __restrict__ gamma,
    const float* __restrict__ beta, float* __restrict__ out,
    int Kdim, int Ncols) {
    __shared__ float As[16][64];
    __shared__ float Bs[16][64];
    const int tid = threadIdx.x;
    const int tx = tid & 15, ty = tid >> 4;
    const long row0 = (long)blockIdx.x * 64;
    const int col0 = blockIdx.y * 64;
    const int rA = tid >> 2, kqA = (tid & 3) << 2;
    const int kkB = tid >> 4, cqB = (tid & 15) << 2;
    float acc[4][4] = {};
    for (int k0 = 0; k0 < Kdim; k0 += 16) {
        const float4 av = *reinterpret_cast<const float4*>(
            A + (row0 + rA) * (long)Kdim + (k0 + kqA));
        const float4 bv = *reinterpret_cast<const float4*>(
            W + (long)(k0 + kkB) * Ncols + (col0 + cqB));
        As[kqA + 0][rA] = av.x;
        As[kqA + 1][rA] = av.y;
        As[kqA + 2][rA] = av.z;
        As[kqA + 3][rA] = av.w;
        *reinterpret_cast<float4*>(&Bs[kkB][cqB]) = bv;
        __syncthreads();
#pragma unroll
        for (int kk = 0; kk < 16; ++kk) {
            float a[4], b[4];
#pragma unroll
            for (int i = 0; i < 4; ++i) a[i] = As[kk][ty * 4 + i];
#pragma unroll
            for (int j = 0; j < 4; ++j) b[j] = Bs[kk][tx * 4 + j];
#pragma unroll
            for (int i = 0; i < 4; ++i)
#pragma unroll
                for (int j = 0; j < 4; ++j) acc[i][j] = fmaf(a[i], b[j], acc[i][j]);
        }
        __syncthreads();
    }
#pragma unroll
    for (int j = 0; j < 4; ++j) {
        const int col = col0 + tx * 4 + j;
        const float bb = bias[col];
        const float gs = BN ? gamma[col] * RS : 0.0f;
        const float bt = BN ? beta[col] : 0.0f;
#pragma unroll
        for (int i = 0; i < 4; ++i) {
            const long row = row0 + ty * 4 + i;
            float v = acc[i][j] + bb;
            if (ACT) v = eluf(v);
            if (BN) v = v * gs + bt;
            out[row * Ncols + col] = v;
        }
    }
}

// ---------------------------------------------------------------------------
// Weight conversion: f32 [K][N] -> bf16 transposed [N][K]. One-shot, tiny.
// ---------------------------------------------------------------------------
__global__ __launch_bounds__(256) void convert_weights(
    const float* __restrict__ d1W, const float* __restrict__ d2W,
    const float* __restrict__ pwW, __hip_bfloat16* __restrict__ d1Wt,
    __hip_bfloat16* __restrict__ d2Wt, __hip_bfloat16* __restrict__ pwWt) {
    const int t = blockIdx.x * 256 + threadIdx.x;
    if (t < 65536) {
        const int k = t >> 8, n = t & 255;
        d1Wt[n * 256 + k] = __float2bfloat16(d1W[t]);
        d2Wt[n * 256 + k] = __float2bfloat16(d2W[t]);
    }
    if (t < 24576) {
        const int k = t >> 7, n = t & 127;
        pwWt[n * 192 + k] = __float2bfloat16(pwW[t]);
    }
}

// ---------------------------------------------------------------------------
// bf16 MFMA GEMM: out[r,c] = post(sum_k A[r,k]*W[k,c] + bias[c])
// A: [M][K] bf16 row-major. Wt: [N][K] bf16 (pre-transposed weights).
// Tile 128x128, BK=32, 256 threads = 4 waves, each wave owns a 64x64 quadrant
// (4x4 fragments of 16x16x32). LDS padded to [128][40] (row stride 80 B ->
// 16B-aligned b128 reads, 2-way bank aliasing = free).
// Fragment maps: A row = lane&15, k = (lane>>4)*8 + j (contiguous b128);
// B (from Wt) col = lane&15, same k map. C/D: col = lane&15,
// row = (lane>>4)*4 + reg  [m89-verified].
// M, Ncols multiples of 128; K multiple of 32.
// ---------------------------------------------------------------------------
template <int ACT, int BN_, int OUTB>
__global__ __launch_bounds__(256) void mfma_gemm(
    const __hip_bfloat16* __restrict__ A, const __hip_bfloat16* __restrict__ Wt,
    const float* __restrict__ bias, const float* __restrict__ gamma,
    const float* __restrict__ beta, void* __restrict__ outp, int K, int Ncols) {
    __shared__ __bf16 As[128][40];
    __shared__ __bf16 Bs[128][40];
    const int tid = threadIdx.x;
    const int w = tid >> 6, l = tid & 63;
    const int wm = w >> 1, wn = w & 1;
    const long row0 = (long)blockIdx.x * 128;
    const int col0 = blockIdx.y * 128;
    const int sr = tid >> 1, sh = tid & 1;  // staging: row, 16-elem half
    const int fr = l & 15, kg = (l >> 4) * 8;
    f32x4 acc[4][4] = {};
    const __hip_bfloat16* __restrict__ ap = A + (row0 + sr) * (long)K + sh * 16;
    const __hip_bfloat16* __restrict__ bp =
        Wt + (long)(col0 + sr) * K + sh * 16;
    for (int k0 = 0; k0 < K; k0 += 32) {
        const uint4 av0 = *reinterpret_cast<const uint4*>(ap + k0);
        const uint4 av1 = *reinterpret_cast<const uint4*>(ap + k0 + 8);
        const uint4 bv0 = *reinterpret_cast<const uint4*>(bp + k0);
        const uint4 bv1 = *reinterpret_cast<const uint4*>(bp + k0 + 8);
        *reinterpret_cast<uint4*>(&As[sr][sh * 16]) = av0;
        *reinterpret_cast<uint4*>(&As[sr][sh * 16 + 8]) = av1;
        *reinterpret_cast<uint4*>(&Bs[sr][sh * 16]) = bv0;
        *reinterpret_cast<uint4*>(&Bs[sr][sh * 16 + 8]) = bv1;
        __syncthreads();
        bf16x8 af[4], bfv[4];
#pragma unroll
        for (int mt = 0; mt < 4; ++mt)
            af[mt] =
                *reinterpret_cast<const bf16x8*>(&As[wm * 64 + mt * 16 + fr][kg]);
#pragma unroll
        for (int nt = 0; nt < 4; ++nt)
            bfv[nt] =
                *reinterpret_cast<const bf16x8*>(&Bs[wn * 64 + nt * 16 + fr][kg]);
#pragma unroll
        for (int mt = 0; mt < 4; ++mt)
#pragma unroll
            for (int nt = 0; nt < 4; ++nt)
                acc[mt][nt] = __builtin_amdgcn_mfma_f32_16x16x32_bf16(
                    af[mt], bfv[nt], acc[mt][nt], 0, 0, 0);
        __syncthreads();
    }
    const int rg = (l >> 4) * 4;
#pragma unroll
    for (int nt = 0; nt < 4; ++nt) {
        const int col = col0 + wn * 64 + nt * 16 + fr;
        const float bb = bias[col];
        const float gs = BN_ ? gamma[col] * RS : 0.0f;
        const float bt = BN_ ? beta[col] : 0.0f;
#pragma unroll
        for (int mt = 0; mt < 4; ++mt) {
#pragma unroll
            for (int r = 0; r < 4; ++r) {
                const long row = row0 + wm * 64 + mt * 16 + rg + r;
                float v = acc[mt][nt][r] + bb;
                if (ACT) v = eluf(v);
                if (BN_) v = v * gs + bt;
                if (OUTB)
                    reinterpret_cast<__hip_bfloat16*>(outp)[row * Ncols + col] =
                        __float2bfloat16(v);
                else
                    reinterpret_cast<float*>(outp)[row * Ncols + col] = v;
            }
        }
    }
}

// ---------------------------------------------------------------------------
// Setup: pts_local (f32 store) + Xc (bf16 store).
// 16 points per block, 256 threads. grid = 2048.
// ---------------------------------------------------------------------------
__global__ __launch_bounds__(256) void setup_kernel(
    const float* __restrict__ rep_pts, const float* __restrict__ pts,
    const int* __restrict__ pts_idx, const float* __restrict__ xt_cW,
    const float* __restrict__ xt_cb, float* __restrict__ pts_local,
    __hip_bfloat16* __restrict__ Xc) {
    __shared__ float cwT[48][256];  // cwT[d*16+k][o] = xt_cW[o,d,k]
    __shared__ float pl2[16][48];   // pl2[pt][d*16+k]
    __shared__ float cb_s[256];
    const int tid = threadIdx.x;
    const long gp0 = (long)blockIdx.x * 16;
#pragma unroll
    for (int i = 0; i < 48; ++i) {
        const int e = i * 256 + tid;
        const int o = e / 48, r = e - o * 48;
        cwT[r][o] = xt_cW[e];
    }
    cb_s[tid] = xt_cb[tid];
    {
        const int pt = tid >> 4, k = tid & 15;
        const long gp = gp0 + pt;
        const int n = (int)(gp >> 11);
        const int idx = pts_idx[gp * 32 + 2 * k];
        const float* ps = pts + ((long)n * 8192 + idx) * 3;
        const float* rs = rep_pts + gp * 3;
        float* plo = pts_local + gp * 48 + k * 3;
#pragma unroll
        for (int d = 0; d < 3; ++d) {
            const float v = ps[d] - rs[d];
            pl2[pt][d * 16 + k] = v;
            plo[d] = v;
        }
    }
    __syncthreads();
    const int o = tid;
    for (int pt = 0; pt < 16; ++pt) {
        float acc = cb_s[o];
#pragma unroll
        for (int i = 0; i < 48; ++i) acc = fmaf(pl2[pt][i], cwT[i][o], acc);
        Xc[(gp0 + pt) * 256 + o] = __float2bfloat16(eluf(acc));
    }
}

// ---------------------------------------------------------------------------
// Final per-point stage (R6 winner): wave-per-point, column-owner,
// SGPR-scalarized uniform reads. Writes dw as bf16 now (feeds MFMA pw GEMM).
// NOTE: no 2nd __launch_bounds__ arg — (256,4) clamped to 64 VGPR and spilled
// 1.4 GB scratch (R4 post-mortem).
// ---------------------------------------------------------------------------
__global__ __launch_bounds__(256) void final_stage_kernel(
    const float* __restrict__ X2,         // [32768][256] f32
    const float* __restrict__ pts_local,  // [32768][48] (k*3+d)
    const int* __restrict__ pts_idx,
    const float* __restrict__ fts_l,  // [16*8192][64]
    const float* __restrict__ d1_W, const float* __restrict__ d1_b,
    const float* __restrict__ d1_g, const float* __restrict__ d1_bt,
    const float* __restrict__ d2_W, const float* __restrict__ d2_b,
    const float* __restrict__ d2_g, const float* __restrict__ d2_bt,
    const float* __restrict__ dw_W, const float* __restrict__ dw_b,
    __hip_bfloat16* __restrict__ dw_out)  // [32768][192] bf16
{
    __shared__ float l0_s[4][16][32];  // wave-private l0
    __shared__ float pl_s[4][48];      // wave-private
    __shared__ float d2s[32][33];      // cooperative: d2_W [q][c], padded

    const int tid = threadIdx.x;
    const int w = tid >> 6;
    const int l = tid & 63;
    const int gp = blockIdx.x * 4 + w;
    const int ugp = __builtin_amdgcn_readfirstlane(gp);  // wave-uniform
    const int n = ugp >> 11;
    const int c32 = l & 31, h = l >> 5;

    if (l < 48) pl_s[w][l] = pts_local[(long)ugp * 48 + l];

#pragma unroll
    for (int i = 0; i < 4; ++i) {
        const int e = i * 256 + tid;  // e = q*32 + c
        d2s[e >> 5][e & 31] = d2_W[e];
    }
    __syncthreads();

    // fts gather (issued early; consumed at fts_X)
    const int* __restrict__ ip = pts_idx + (long)ugp * 32;
    const int colg = (l < 32) ? (32 + l) : (l - 32);
    const float* __restrict__ fbase = fts_l + (long)n * 8192 * 64 + colg;
    float fg[16];
#pragma unroll
    for (int j = 0; j < 16; ++j) fg[j] = fbase[(long)ip[2 * j] * 64];

    // l0
    {
        const float w0 = d1_W[0 * 32 + c32], w1 = d1_W[1 * 32 + c32],
                    w2 = d1_W[2 * 32 + c32];
        const float b = d1_b[c32], gsc = d1_g[c32] * RS, bt = d1_bt[c32];
#pragma unroll
        for (int jl = 0; jl < 8; ++jl) {
            const int j = h * 8 + jl;
            float a = b;
            a = fmaf(pl_s[w][j * 3 + 0], w0, a);
            a = fmaf(pl_s[w][j * 3 + 1], w1, a);
            a = fmaf(pl_s[w][j * 3 + 2], w2, a);
            a = eluf(a);
            l0_s[w][j][c32] = a * gsc + bt;
        }
    }

    // lifted
    float lf[8];
    {
        const float b = d2_b[c32];
#pragma unroll
        for (int jl = 0; jl < 8; ++jl) lf[jl] = b;
#pragma unroll
        for (int q4 = 0; q4 < 8; ++q4) {
            const float w0 = d2s[q4 * 4 + 0][c32];
            const float w1 = d2s[q4 * 4 + 1][c32];
            const float w2 = d2s[q4 * 4 + 2][c32];
            const float w3 = d2s[q4 * 4 + 3][c32];
#pragma unroll
            for (int jl = 0; jl < 8; ++jl) {
                const float4 lv = *reinterpret_cast<const float4*>(
                    &l0_s[w][h * 8 + jl][q4 * 4]);
                lf[jl] = fmaf(lv.x, w0, lf[jl]);
                lf[jl] = fmaf(lv.y, w1, lf[jl]);
                lf[jl] = fmaf(lv.z, w2, lf[jl]);
                lf[jl] = fmaf(lv.w, w3, lf[jl]);
            }
        }
        const float gsc = d2_g[c32] * RS, bt = d2_bt[c32];
#pragma unroll
        for (int jl = 0; jl < 8; ++jl) lf[jl] = eluf(lf[jl]) * gsc + bt;
    }

    // fA via shfl_xor(32)
    float fA[16];
#pragma unroll
    for (int j = 0; j < 8; ++j) {
        const float other = __shfl_xor(lf[j], 32);
        fA[j] = (l < 32) ? lf[j] : fg[j];
        fA[j + 8] = (l < 32) ? other : fg[j + 8];
    }

    // fts_X with s_load X row
    const float* __restrict__ Xu = X2 + (long)ugp * 256;
    float accA[16], accB[16];
#pragma unroll
    for (int i = 0; i < 16; ++i) {
        accA[i] = 0.0f;
        accB[i] = 0.0f;
    }
#pragma unroll
    for (int i = 0; i < 16; ++i) {
#pragma unroll
        for (int j = 0; j < 16; ++j) {
            const float xs = Xu[i * 16 + j];
            accA[i] = fmaf(xs, fA[j], accA[i]);
            accB[i] = fmaf(xs, fg[j], accB[i]);
        }
    }

    // dw (bf16 out)
    {
        float o0 = dw_b[2 * l + 0], o1 = dw_b[2 * l + 1];
        const float4* __restrict__ wp0 =
            reinterpret_cast<const float4*>(dw_W + l * 32);
        const float4* __restrict__ wp1 =
            reinterpret_cast<const float4*>(dw_W + l * 32 + 16);
#pragma unroll
        for (int q = 0; q < 4; ++q) {
            const float4 w0 = wp0[q], w1 = wp1[q];
            o0 = fmaf(accA[q * 4 + 0], w0.x, o0);
            o0 = fmaf(accA[q * 4 + 1], w0.y, o0);
            o0 = fmaf(accA[q * 4 + 2], w0.z, o0);
            o0 = fmaf(accA[q * 4 + 3], w0.w, o0);
            o1 = fmaf(accA[q * 4 + 0], w1.x, o1);
            o1 = fmaf(accA[q * 4 + 1], w1.y, o1);
            o1 = fmaf(accA[q * 4 + 2], w1.z, o1);
            o1 = fmaf(accA[q * 4 + 3], w1.w, o1);
        }
        __hip_bfloat162 pk;
        pk.x = __float2bfloat16(o0);
        pk.y = __float2bfloat16(o1);
        *reinterpret_cast<__hip_bfloat162*>(dw_out + (long)gp * 192 + 2 * l) =
            pk;
        if (l < 32) {
            const int c1 = 64 + l;
            float p0 = dw_b[2 * c1 + 0], p1 = dw_b[2 * c1 + 1];
            const float4* __restrict__ vp0 =
                reinterpret_cast<const float4*>(dw_W + c1 * 32);
            const float4* __restrict__ vp1 =
                reinterpret_cast<const float4*>(dw_W + c1 * 32 + 16);
#pragma unroll
            for (int q = 0; q < 4; ++q) {
                const float4 w0 = vp0[q], w1 = vp1[q];
                p0 = fmaf(accB[q * 4 + 0], w0.x, p0);
                p0 = fmaf(accB[q * 4 + 1], w0.y, p0);
                p0 = fmaf(accB[q * 4 + 2], w0.z, p0);
                p0 = fmaf(accB[q * 4 + 3], w0.w, p0);
                p1 = fmaf(accB[q * 4 + 0], w1.x, p1);
                p1 = fmaf(accB[q * 4 + 1], w1.y, p1);
                p1 = fmaf(accB[q * 4 + 2], w1.z, p1);
                p1 = fmaf(accB[q * 4 + 3], w1.w, p1);
            }
            __hip_bfloat162 pk2;
            pk2.x = __float2bfloat16(p0);
            pk2.y = __float2bfloat16(p1);
            *reinterpret_cast<__hip_bfloat162*>(dw_out + (long)gp * 192 +
                                                2 * c1) = pk2;
        }
    }
}

extern "C" void kernel_launch(void* const* d_in, const int* in_sizes, int n_in,
                              void* d_out, int out_size, void* d_ws,
                              size_t ws_size, hipStream_t stream) {
    const float* rep_pts = (const float*)d_in[0];
    const float* pts = (const float*)d_in[1];
    const float* fts = (const float*)d_in[2];
    const int* pts_idx = (const int*)d_in[3];
    const float* dense_W = (const float*)d_in[4];
    const float* dense_b = (const float*)d_in[5];
    const float* dense_g = (const float*)d_in[6];
    const float* dense_bt = (const float*)d_in[7];
    const float* d1_W = (const float*)d_in[8];
    const float* d1_b = (const float*)d_in[9];
    const float* d1_g = (const float*)d_in[10];
    const float* d1_bt = (const float*)d_in[11];
    const float* d2_W = (const float*)d_in[12];
    const float* d2_b = (const float*)d_in[13];
    const float* d2_g = (const float*)d_in[14];
    const float* d2_bt = (const float*)d_in[15];
    const float* xt_cW = (const float*)d_in[16];
    const float* xt_cb = (const float*)d_in[17];
    const float* xt_d1W = (const float*)d_in[18];
    const float* xt_d1b = (const float*)d_in[19];
    const float* xt_d2W = (const float*)d_in[20];
    const float* xt_d2b = (const float*)d_in[21];
    const float* dw_W = (const float*)d_in[22];
    const float* dw_b = (const float*)d_in[23];
    const float* pw_W = (const float*)d_in[24];
    const float* pw_b = (const float*)d_in[25];
    const float* sep_g = (const float*)d_in[26];
    const float* sep_bt = (const float*)d_in[27];

    float* ws = (float*)d_ws;
    // layout (f32 slots). dw_bf16 overlays Xc_bf16 (Xc dead after X1 GEMM).
    float* fts_l = ws;                                        // 8388608 f32
    float* X2f = ws + 8388608;                                // 8388608 f32
    __hip_bfloat16* XcB = (__hip_bfloat16*)(ws + 16777216);   // 8388608 bf16
    __hip_bfloat16* dwB = (__hip_bfloat16*)(ws + 16777216);   // 6291456 bf16
    __hip_bfloat16* X1B = (__hip_bfloat16*)(ws + 20971520);   // 8388608 bf16
    float* pl = ws + 25165824;                                // 1572864 f32
    __hip_bfloat16* d1Wt = (__hip_bfloat16*)(ws + 26738688);  // 65536 bf16
    __hip_bfloat16* d2Wt = (__hip_bfloat16*)(ws + 26771456);  // 65536 bf16
    __hip_bfloat16* pwWt = (__hip_bfloat16*)(ws + 26804224);  // 24576 bf16

    // 0) weight convert+transpose to bf16
    convert_weights<<<256, 256, 0, stream>>>(xt_d1W, xt_d2W, pw_W, d1Wt, d2Wt,
                                             pwWt);

    // 1) fts_l = bn(elu(fts @ dense_W + b))  f32 GEMM (f32 input)
    gemm_bias_act<1, 1><<<dim3(2048, 1), 256, 0, stream>>>(
        fts, dense_W, dense_b, dense_g, dense_bt, fts_l, 64, 64);

    // 2) pts_local + Xc (bf16)
    setup_kernel<<<2048, 256, 0, stream>>>(rep_pts, pts, pts_idx, xt_cW, xt_cb,
                                           pl, XcB);

    // 3) X1 = elu(Xc @ xt_d1W + b)  bf16 MFMA -> bf16
    mfma_gemm<1, 0, 1><<<dim3(256, 2), 256, 0, stream>>>(
        XcB, d1Wt, xt_d1b, nullptr, nullptr, X1B, 256, 256);

    // 4) X2 = X1 @ xt_d2W + b  bf16 MFMA -> f32
    mfma_gemm<0, 0, 0><<<dim3(256, 2), 256, 0, stream>>>(
        X1B, d2Wt, xt_d2b, nullptr, nullptr, X2f, 256, 256);

    // 5) lifted/gather/fts_X/dw -> dwB (bf16)
    final_stage_kernel<<<8192, 256, 0, stream>>>(
        X2f, pl, pts_idx, fts_l, d1_W, d1_b, d1_g, d1_bt, d2_W, d2_b, d2_g,
        d2_bt, dw_W, dw_b, dwB);

    // 6) out = bn(elu(dw @ pw_W + pw_b))  bf16 MFMA -> f32
    mfma_gemm<1, 1, 0><<<dim3(256, 1), 256, 0, stream>>>(
        dwB, pwWt, pw_b, sep_g, sep_bt, d_out, 192, 128);
}

// Round 8
// 191.491 us; speedup vs baseline: 3.4542x; 1.1503x over previous
//
#include <hip/hip_runtime.h>
#include <hip/hip_bf16.h>

#define RS 0.9999950000374998f  // 1/sqrt(1+1e-5)

__device__ __forceinline__ float eluf(float x) {
    return x > 0.0f ? x : __expf(x) - 1.0f;
}

typedef __attribute__((ext_vector_type(8))) __bf16 bf16x8;
typedef __attribute__((ext_vector_type(4))) float f32x4;
typedef __attribute__((ext_vector_type(4))) unsigned int u32x4;

// ---------------------------------------------------------------------------
// f32 tiled GEMM (kept for fts_l whose input is f32).
// ---------------------------------------------------------------------------
template <int ACT, int BN>
__global__ __launch_bounds__(256) void gemm_bias_act(
    const float* __restrict__ A, const float* __restrict__ W,
    const float* __restrict__ bias, const float* __restrict__ gamma,
    const float* __restrict__ beta, float* __restrict__ out,
    int Kdim, int Ncols) {
    __shared__ float As[16][64];
    __shared__ float Bs[16][64];
    const int tid = threadIdx.x;
    const int tx = tid & 15, ty = tid >> 4;
    const long row0 = (long)blockIdx.x * 64;
    const int col0 = blockIdx.y * 64;
    const int rA = tid >> 2, kqA = (tid & 3) << 2;
    const int kkB = tid >> 4, cqB = (tid & 15) << 2;
    float acc[4][4] = {};
    for (int k0 = 0; k0 < Kdim; k0 += 16) {
        const float4 av = *reinterpret_cast<const float4*>(
            A + (row0 + rA) * (long)Kdim + (k0 + kqA));
        const float4 bv = *reinterpret_cast<const float4*>(
            W + (long)(k0 + kkB) * Ncols + (col0 + cqB));
        As[kqA + 0][rA] = av.x;
        As[kqA + 1][rA] = av.y;
        As[kqA + 2][rA] = av.z;
        As[kqA + 3][rA] = av.w;
        *reinterpret_cast<float4*>(&Bs[kkB][cqB]) = bv;
        __syncthreads();
#pragma unroll
        for (int kk = 0; kk < 16; ++kk) {
            float a[4], b[4];
#pragma unroll
            for (int i = 0; i < 4; ++i) a[i] = As[kk][ty * 4 + i];
#pragma unroll
            for (int j = 0; j < 4; ++j) b[j] = Bs[kk][tx * 4 + j];
#pragma unroll
            for (int i = 0; i < 4; ++i)
#pragma unroll
                for (int j = 0; j < 4; ++j) acc[i][j] = fmaf(a[i], b[j], acc[i][j]);
        }
        __syncthreads();
    }
#pragma unroll
    for (int j = 0; j < 4; ++j) {
        const int col = col0 + tx * 4 + j;
        const float bb = bias[col];
        const float gs = BN ? gamma[col] * RS : 0.0f;
        const float bt = BN ? beta[col] : 0.0f;
#pragma unroll
        for (int i = 0; i < 4; ++i) {
            const long row = row0 + ty * 4 + i;
            float v = acc[i][j] + bb;
            if (ACT) v = eluf(v);
            if (BN) v = v * gs + bt;
            out[row * Ncols + col] = v;
        }
    }
}

// ---------------------------------------------------------------------------
// Weight conversion to bf16-transposed forms. One-shot, tiny.
// xt_d1W/xt_d2W: [256][256] -> [N][K]; pw_W: [192][128] -> [128][192];
// d2_W (point-lift): [32][32] -> [c][q].
// ---------------------------------------------------------------------------
__global__ __launch_bounds__(256) void convert_weights(
    const float* __restrict__ d1W, const float* __restrict__ d2W,
    const float* __restrict__ pwW, const float* __restrict__ d2Ws,
    __hip_bfloat16* __restrict__ d1Wt, __hip_bfloat16* __restrict__ d2Wt,
    __hip_bfloat16* __restrict__ pwWt, __hip_bfloat16* __restrict__ d2pWt) {
    const int t = blockIdx.x * 256 + threadIdx.x;
    if (t < 65536) {
        const int k = t >> 8, n = t & 255;
        d1Wt[n * 256 + k] = __float2bfloat16(d1W[t]);
        d2Wt[n * 256 + k] = __float2bfloat16(d2W[t]);
    }
    if (t < 24576) {
        const int k = t >> 7, n = t & 127;
        pwWt[n * 192 + k] = __float2bfloat16(pwW[t]);
    }
    if (t < 1024) {
        const int q = t >> 5, c = t & 31;
        d2pWt[c * 32 + q] = __float2bfloat16(d2Ws[t]);
    }
}

// ---------------------------------------------------------------------------
// bf16 MFMA GEMM (R7 winner): out = post(A @ Wt^T + bias), Wt pre-transposed.
// Tile 128x128, BK=32, 4 waves. See R7 comments.
// ---------------------------------------------------------------------------
template <int ACT, int BN_, int OUTB>
__global__ __launch_bounds__(256) void mfma_gemm(
    const __hip_bfloat16* __restrict__ A, const __hip_bfloat16* __restrict__ Wt,
    const float* __restrict__ bias, const float* __restrict__ gamma,
    const float* __restrict__ beta, void* __restrict__ outp, int K, int Ncols) {
    __shared__ __bf16 As[128][40];
    __shared__ __bf16 Bs[128][40];
    const int tid = threadIdx.x;
    const int w = tid >> 6, l = tid & 63;
    const int wm = w >> 1, wn = w & 1;
    const long row0 = (long)blockIdx.x * 128;
    const int col0 = blockIdx.y * 128;
    const int sr = tid >> 1, sh = tid & 1;
    const int fr = l & 15, kg = (l >> 4) * 8;
    f32x4 acc[4][4] = {};
    const __hip_bfloat16* __restrict__ ap = A + (row0 + sr) * (long)K + sh * 16;
    const __hip_bfloat16* __restrict__ bp =
        Wt + (long)(col0 + sr) * K + sh * 16;
    for (int k0 = 0; k0 < K; k0 += 32) {
        const uint4 av0 = *reinterpret_cast<const uint4*>(ap + k0);
        const uint4 av1 = *reinterpret_cast<const uint4*>(ap + k0 + 8);
        const uint4 bv0 = *reinterpret_cast<const uint4*>(bp + k0);
        const uint4 bv1 = *reinterpret_cast<const uint4*>(bp + k0 + 8);
        *reinterpret_cast<uint4*>(&As[sr][sh * 16]) = av0;
        *reinterpret_cast<uint4*>(&As[sr][sh * 16 + 8]) = av1;
        *reinterpret_cast<uint4*>(&Bs[sr][sh * 16]) = bv0;
        *reinterpret_cast<uint4*>(&Bs[sr][sh * 16 + 8]) = bv1;
        __syncthreads();
        bf16x8 af[4], bfv[4];
#pragma unroll
        for (int mt = 0; mt < 4; ++mt)
            af[mt] =
                *reinterpret_cast<const bf16x8*>(&As[wm * 64 + mt * 16 + fr][kg]);
#pragma unroll
        for (int nt = 0; nt < 4; ++nt)
            bfv[nt] =
                *reinterpret_cast<const bf16x8*>(&Bs[wn * 64 + nt * 16 + fr][kg]);
#pragma unroll
        for (int mt = 0; mt < 4; ++mt)
#pragma unroll
            for (int nt = 0; nt < 4; ++nt)
                acc[mt][nt] = __builtin_amdgcn_mfma_f32_16x16x32_bf16(
                    af[mt], bfv[nt], acc[mt][nt], 0, 0, 0);
        __syncthreads();
    }
    const int rg = (l >> 4) * 4;
#pragma unroll
    for (int nt = 0; nt < 4; ++nt) {
        const int col = col0 + wn * 64 + nt * 16 + fr;
        const float bb = bias[col];
        const float gs = BN_ ? gamma[col] * RS : 0.0f;
        const float bt = BN_ ? beta[col] : 0.0f;
#pragma unroll
        for (int mt = 0; mt < 4; ++mt) {
#pragma unroll
            for (int r = 0; r < 4; ++r) {
                const long row = row0 + wm * 64 + mt * 16 + rg + r;
                float v = acc[mt][nt][r] + bb;
                if (ACT) v = eluf(v);
                if (BN_) v = v * gs + bt;
                if (OUTB)
                    reinterpret_cast<__hip_bfloat16*>(outp)[row * Ncols + col] =
                        __float2bfloat16(v);
                else
                    reinterpret_cast<float*>(outp)[row * Ncols + col] = v;
            }
        }
    }
}

// ---------------------------------------------------------------------------
// Setup: pts_local (f32 store) + Xc (bf16 store). 16 pts/block, grid 2048.
// ---------------------------------------------------------------------------
__global__ __launch_bounds__(256) void setup_kernel(
    const float* __restrict__ rep_pts, const float* __restrict__ pts,
    const int* __restrict__ pts_idx, const float* __restrict__ xt_cW,
    const float* __restrict__ xt_cb, float* __restrict__ pts_local,
    __hip_bfloat16* __restrict__ Xc) {
    __shared__ float cwT[48][256];
    __shared__ float pl2[16][48];
    __shared__ float cb_s[256];
    const int tid = threadIdx.x;
    const long gp0 = (long)blockIdx.x * 16;
#pragma unroll
    for (int i = 0; i < 48; ++i) {
        const int e = i * 256 + tid;
        const int o = e / 48, r = e - o * 48;
        cwT[r][o] = xt_cW[e];
    }
    cb_s[tid] = xt_cb[tid];
    {
        const int pt = tid >> 4, k = tid & 15;
        const long gp = gp0 + pt;
        const int n = (int)(gp >> 11);
        const int idx = pts_idx[gp * 32 + 2 * k];
        const float* ps = pts + ((long)n * 8192 + idx) * 3;
        const float* rs = rep_pts + gp * 3;
        float* plo = pts_local + gp * 48 + k * 3;
#pragma unroll
        for (int d = 0; d < 3; ++d) {
            const float v = ps[d] - rs[d];
            pl2[pt][d * 16 + k] = v;
            plo[d] = v;
        }
    }
    __syncthreads();
    const int o = tid;
    for (int pt = 0; pt < 16; ++pt) {
        float acc = cb_s[o];
#pragma unroll
        for (int i = 0; i < 48; ++i) acc = fmaf(pl2[pt][i], cwT[i][o], acc);
        Xc[(gp0 + pt) * 256 + o] = __float2bfloat16(eluf(acc));
    }
}

// ---------------------------------------------------------------------------
// Final per-point stage v6: wave-per-point, MFMA for lifted and fts_X.
// Block = 256 = 4 waves = 4 points; grid 8192. NO barriers (all LDS
// wave-private). fcat LDS tile [96 cols][24 k] bf16 (48B rows, 16B-aligned).
//   cols 0..31 = lifted, cols 32..95 = gathered fts cols 0..63; k = neighbor.
// fts_X = X(16x16, A-frag from bf16 X2) @ fcat (6 B-frags), K padded 16->32
// with BOTH operands masked to 0 for lanes>=32 (avoid 0*NaN from uninit LDS).
// dw: per-lane 4-row partials + shfl_xor(16/32) butterfly.
// NOTE: no 2nd __launch_bounds__ arg (R4: (256,4) clamp -> 64 VGPR spill).
// ---------------------------------------------------------------------------
__global__ __launch_bounds__(256) void final_stage_kernel(
    const __hip_bfloat16* __restrict__ X2B,  // [32768][256] bf16
    const float* __restrict__ pts_local,     // [32768][48] (k*3+d)
    const int* __restrict__ pts_idx,
    const float* __restrict__ fts_l,  // [131072][64] f32
    const float* __restrict__ d1_W, const float* __restrict__ d1_b,
    const float* __restrict__ d1_g, const float* __restrict__ d1_bt,
    const __hip_bfloat16* __restrict__ d2pWt,  // [32 c][32 q] bf16
    const float* __restrict__ d2_b, const float* __restrict__ d2_g,
    const float* __restrict__ d2_bt, const float* __restrict__ dw_W,
    const float* __restrict__ dw_b,
    __hip_bfloat16* __restrict__ dw_out)  // [32768][192] bf16
{
    __shared__ __bf16 fcat[4][96][24];  // wave-private
    __shared__ float pl_s[4][48];       // wave-private

    const int tid = threadIdx.x;
    const int w = tid >> 6, l = tid & 63;
    const int gp = blockIdx.x * 4 + w;
    const int ugp = __builtin_amdgcn_readfirstlane(gp);  // wave-uniform
    const int n = ugp >> 11;
    const int fr = l & 15;        // fragment row/col within 16
    const int kg = (l >> 4) * 8;  // k-chunk start: 0,8,16,24
    const int kk = kg & 15;       // wrapped: 0,8
    const unsigned msk = (l < 32) ? 0xFFFFFFFFu : 0u;
    const int rg4 = (l >> 4) * 4;

    if (l < 48) pl_s[w][l] = pts_local[(long)ugp * 48 + l];

    // ---- fts gather: lane owns fts col colg, 16 rows (idx via s_load) ----
    const int* __restrict__ ip = pts_idx + (long)ugp * 32;
    const int colg = (l < 32) ? (32 + l) : (l - 32);
    const float* __restrict__ fbase = fts_l + (long)n * 8192 * 64 + colg;
    float fg[16];
#pragma unroll
    for (int j = 0; j < 16; ++j) fg[j] = fbase[(long)ip[2 * j] * 64];

    // ---- l0 row-owner into A-frag: lane = row fr, k-cols kg..kg+7 ----
    bf16x8 a_l0;
    {
        const float p0 = pl_s[w][fr * 3 + 0];
        const float p1 = pl_s[w][fr * 3 + 1];
        const float p2 = pl_s[w][fr * 3 + 2];
#pragma unroll
        for (int jj = 0; jj < 8; ++jj) {
            const int q = kg + jj;
            float a = d1_b[q];
            a = fmaf(p0, d1_W[q], a);
            a = fmaf(p1, d1_W[32 + q], a);
            a = fmaf(p2, d1_W[64 + q], a);
            a = eluf(a);
            a = a * (d1_g[q] * RS) + d1_bt[q];
            a_l0[jj] = (__bf16)a;
        }
    }

    // ---- lifted = l0 @ d2_W via 2 MFMA (K=32 exact) ----
    {
        const bf16x8 b0 =
            *reinterpret_cast<const bf16x8*>(d2pWt + (0 + fr) * 32 + kg);
        const bf16x8 b1 =
            *reinterpret_cast<const bf16x8*>(d2pWt + (16 + fr) * 32 + kg);
        f32x4 lif0 = {}, lif1 = {};
        lif0 = __builtin_amdgcn_mfma_f32_16x16x32_bf16(a_l0, b0, lif0, 0, 0, 0);
        lif1 = __builtin_amdgcn_mfma_f32_16x16x32_bf16(a_l0, b1, lif1, 0, 0, 0);
        // epilogue + write 4 bf16 (8B) into fcat[col][rg4]
#pragma unroll
        for (int f = 0; f < 2; ++f) {
            const int c = f * 16 + fr;
            const float bb = d2_b[c], gs = d2_g[c] * RS, bt = d2_bt[c];
            const f32x4 dd = f ? lif1 : lif0;
            ushort pk[4];
#pragma unroll
            for (int r = 0; r < 4; ++r) {
                float v = dd[r] + bb;
                v = eluf(v) * gs + bt;
                const __bf16 h = (__bf16)v;
                pk[r] = *reinterpret_cast<const ushort*>(&h);
            }
            *reinterpret_cast<uint2*>(&fcat[w][c][rg4]) =
                make_uint2((unsigned)pk[0] | ((unsigned)pk[1] << 16),
                           (unsigned)pk[2] | ((unsigned)pk[3] << 16));
        }
    }

    // ---- fg -> bf16 -> fcat[32+colg][0..15] (2 x ds_write_b128) ----
    {
        bf16x8 lo, hi;
#pragma unroll
        for (int jj = 0; jj < 8; ++jj) {
            lo[jj] = (__bf16)fg[jj];
            hi[jj] = (__bf16)fg[8 + jj];
        }
        *reinterpret_cast<bf16x8*>(&fcat[w][32 + colg][0]) = lo;
        *reinterpret_cast<bf16x8*>(&fcat[w][32 + colg][8]) = hi;
    }

    // ---- A-frag: X row fr, k=kk..kk+7 from bf16 X2 (zero for lanes>=32) ----
    u32x4 axu =
        *reinterpret_cast<const u32x4*>(X2B + (long)ugp * 256 + fr * 16 + kk);
    axu &= msk;
    const bf16x8 ax = *reinterpret_cast<const bf16x8*>(&axu);

    // ---- fts_X: 6 B-frags from fcat + 6 MFMA ----
    f32x4 acc[6];
#pragma unroll
    for (int f = 0; f < 6; ++f) acc[f] = (f32x4){};
#pragma unroll
    for (int f = 0; f < 6; ++f) {
        u32x4 bu =
            *reinterpret_cast<const u32x4*>(&fcat[w][f * 16 + fr][kk]);
        bu &= msk;  // zero k>=16 (also kills uninit-LDS NaN)
        const bf16x8 bf = *reinterpret_cast<const bf16x8*>(&bu);
        acc[f] = __builtin_amdgcn_mfma_f32_16x16x32_bf16(ax, bf, acc[f], 0, 0, 0);
    }

    // ---- dw: partials over rows rg4..rg4+3, butterfly over lane groups ----
    float dwv[6][2];
#pragma unroll
    for (int f = 0; f < 6; ++f) {
        const int c = f * 16 + fr;
        const float4 w0 = *reinterpret_cast<const float4*>(dw_W + c * 32 + rg4);
        const float4 w1 =
            *reinterpret_cast<const float4*>(dw_W + c * 32 + 16 + rg4);
        float p0 = acc[f][0] * w0.x;
        p0 = fmaf(acc[f][1], w0.y, p0);
        p0 = fmaf(acc[f][2], w0.z, p0);
        p0 = fmaf(acc[f][3], w0.w, p0);
        float p1 = acc[f][0] * w1.x;
        p1 = fmaf(acc[f][1], w1.y, p1);
        p1 = fmaf(acc[f][2], w1.z, p1);
        p1 = fmaf(acc[f][3], w1.w, p1);
        p0 += __shfl_xor(p0, 16);
        p0 += __shfl_xor(p0, 32);
        p1 += __shfl_xor(p1, 16);
        p1 += __shfl_xor(p1, 32);
        dwv[f][0] = p0;
        dwv[f][1] = p1;
    }
    if (l < 16) {
#pragma unroll
        for (int f = 0; f < 6; ++f) {
            const int c = f * 16 + l;
            __hip_bfloat162 pk;
            pk.x = __float2bfloat16(dwv[f][0] + dw_b[2 * c + 0]);
            pk.y = __float2bfloat16(dwv[f][1] + dw_b[2 * c + 1]);
            *reinterpret_cast<__hip_bfloat162*>(dw_out + (long)gp * 192 +
                                                2 * c) = pk;
        }
    }
}

extern "C" void kernel_launch(void* const* d_in, const int* in_sizes, int n_in,
                              void* d_out, int out_size, void* d_ws,
                              size_t ws_size, hipStream_t stream) {
    const float* rep_pts = (const float*)d_in[0];
    const float* pts = (const float*)d_in[1];
    const float* fts = (const float*)d_in[2];
    const int* pts_idx = (const int*)d_in[3];
    const float* dense_W = (const float*)d_in[4];
    const float* dense_b = (const float*)d_in[5];
    const float* dense_g = (const float*)d_in[6];
    const float* dense_bt = (const float*)d_in[7];
    const float* d1_W = (const float*)d_in[8];
    const float* d1_b = (const float*)d_in[9];
    const float* d1_g = (const float*)d_in[10];
    const float* d1_bt = (const float*)d_in[11];
    const float* d2_W = (const float*)d_in[12];
    const float* d2_b = (const float*)d_in[13];
    const float* d2_g = (const float*)d_in[14];
    const float* d2_bt = (const float*)d_in[15];
    const float* xt_cW = (const float*)d_in[16];
    const float* xt_cb = (const float*)d_in[17];
    const float* xt_d1W = (const float*)d_in[18];
    const float* xt_d1b = (const float*)d_in[19];
    const float* xt_d2W = (const float*)d_in[20];
    const float* xt_d2b = (const float*)d_in[21];
    const float* dw_W = (const float*)d_in[22];
    const float* dw_b = (const float*)d_in[23];
    const float* pw_W = (const float*)d_in[24];
    const float* pw_b = (const float*)d_in[25];
    const float* sep_g = (const float*)d_in[26];
    const float* sep_bt = (const float*)d_in[27];

    float* ws = (float*)d_ws;
    // layout (f32 slots). dwB overlays XcB (Xc dead after X1 GEMM).
    float* fts_l = ws;                                         // 8388608 f32
    __hip_bfloat16* X2Bb = (__hip_bfloat16*)(ws + 8388608);    // 8388608 bf16
    __hip_bfloat16* XcB = (__hip_bfloat16*)(ws + 16777216);    // 8388608 bf16
    __hip_bfloat16* dwB = (__hip_bfloat16*)(ws + 16777216);    // 6291456 bf16
    __hip_bfloat16* X1B = (__hip_bfloat16*)(ws + 20971520);    // 8388608 bf16
    float* pl = ws + 25165824;                                 // 1572864 f32
    __hip_bfloat16* d1Wt = (__hip_bfloat16*)(ws + 26738688);   // 65536 bf16
    __hip_bfloat16* d2Wt = (__hip_bfloat16*)(ws + 26771456);   // 65536 bf16
    __hip_bfloat16* pwWt = (__hip_bfloat16*)(ws + 26804224);   // 24576 bf16
    __hip_bfloat16* d2pWt = (__hip_bfloat16*)(ws + 26816512);  // 1024 bf16

    // 0) weight convert+transpose to bf16
    convert_weights<<<256, 256, 0, stream>>>(xt_d1W, xt_d2W, pw_W, d2_W, d1Wt,
                                             d2Wt, pwWt, d2pWt);

    // 1) fts_l = bn(elu(fts @ dense_W + b))  f32 GEMM
    gemm_bias_act<1, 1><<<dim3(2048, 1), 256, 0, stream>>>(
        fts, dense_W, dense_b, dense_g, dense_bt, fts_l, 64, 64);

    // 2) pts_local + Xc (bf16)
    setup_kernel<<<2048, 256, 0, stream>>>(rep_pts, pts, pts_idx, xt_cW, xt_cb,
                                           pl, XcB);

    // 3) X1 = elu(Xc @ xt_d1W + b)  bf16 MFMA -> bf16
    mfma_gemm<1, 0, 1><<<dim3(256, 2), 256, 0, stream>>>(
        XcB, d1Wt, xt_d1b, nullptr, nullptr, X1B, 256, 256);

    // 4) X2 = X1 @ xt_d2W + b  bf16 MFMA -> bf16 (feeds A-frags directly)
    mfma_gemm<0, 0, 1><<<dim3(256, 2), 256, 0, stream>>>(
        X1B, d2Wt, xt_d2b, nullptr, nullptr, X2Bb, 256, 256);

    // 5) lifted/gather/fts_X/dw -> dwB (bf16)
    final_stage_kernel<<<8192, 256, 0, stream>>>(
        X2Bb, pl, pts_idx, fts_l, d1_W, d1_b, d1_g, d1_bt, d2pWt, d2_b, d2_g,
        d2_bt, dw_W, dw_b, dwB);

    // 6) out = bn(elu(dw @ pw_W + pw_b))  bf16 MFMA -> f32
    mfma_gemm<1, 1, 0><<<dim3(256, 1), 256, 0, stream>>>(
        dwB, pwWt, pw_b, sep_g, sep_bt, d_out, 192, 128);
}

// Round 9
// 188.957 us; speedup vs baseline: 3.5005x; 1.0134x over previous
//
#include <hip/hip_runtime.h>
#include <hip/hip_bf16.h>

#define RS 0.9999950000374998f  // 1/sqrt(1+1e-5)

__device__ __forceinline__ float eluf(float x) {
    return x > 0.0f ? x : __expf(x) - 1.0f;
}

typedef __attribute__((ext_vector_type(8))) __bf16 bf16x8;
typedef __attribute__((ext_vector_type(4))) float f32x4;
typedef __attribute__((ext_vector_type(4))) unsigned int u32x4;

// ---------------------------------------------------------------------------
// f32-input tiled GEMM (fts_l). OUTB=1 -> bf16 output.
// ---------------------------------------------------------------------------
template <int ACT, int BN, int OUTB>
__global__ __launch_bounds__(256) void gemm_bias_act(
    const float* __restrict__ A, const float* __restrict__ W,
    const float* __restrict__ bias, const float* __restrict__ gamma,
    const float* __restrict__ beta, void* __restrict__ outp,
    int Kdim, int Ncols) {
    __shared__ float As[16][64];
    __shared__ float Bs[16][64];
    const int tid = threadIdx.x;
    const int tx = tid & 15, ty = tid >> 4;
    const long row0 = (long)blockIdx.x * 64;
    const int col0 = blockIdx.y * 64;
    const int rA = tid >> 2, kqA = (tid & 3) << 2;
    const int kkB = tid >> 4, cqB = (tid & 15) << 2;
    float acc[4][4] = {};
    for (int k0 = 0; k0 < Kdim; k0 += 16) {
        const float4 av = *reinterpret_cast<const float4*>(
            A + (row0 + rA) * (long)Kdim + (k0 + kqA));
        const float4 bv = *reinterpret_cast<const float4*>(
            W + (long)(k0 + kkB) * Ncols + (col0 + cqB));
        As[kqA + 0][rA] = av.x;
        As[kqA + 1][rA] = av.y;
        As[kqA + 2][rA] = av.z;
        As[kqA + 3][rA] = av.w;
        *reinterpret_cast<float4*>(&Bs[kkB][cqB]) = bv;
        __syncthreads();
#pragma unroll
        for (int kk = 0; kk < 16; ++kk) {
            float a[4], b[4];
#pragma unroll
            for (int i = 0; i < 4; ++i) a[i] = As[kk][ty * 4 + i];
#pragma unroll
            for (int j = 0; j < 4; ++j) b[j] = Bs[kk][tx * 4 + j];
#pragma unroll
            for (int i = 0; i < 4; ++i)
#pragma unroll
                for (int j = 0; j < 4; ++j) acc[i][j] = fmaf(a[i], b[j], acc[i][j]);
        }
        __syncthreads();
    }
#pragma unroll
    for (int j = 0; j < 4; ++j) {
        const int col = col0 + tx * 4 + j;
        const float bb = bias[col];
        const float gs = BN ? gamma[col] * RS : 0.0f;
        const float bt = BN ? beta[col] : 0.0f;
#pragma unroll
        for (int i = 0; i < 4; ++i) {
            const long row = row0 + ty * 4 + i;
            float v = acc[i][j] + bb;
            if (ACT) v = eluf(v);
            if (BN) v = v * gs + bt;
            if (OUTB)
                reinterpret_cast<__hip_bfloat16*>(outp)[row * Ncols + col] =
                    __float2bfloat16(v);
            else
                reinterpret_cast<float*>(outp)[row * Ncols + col] = v;
        }
    }
}

// ---------------------------------------------------------------------------
// Weight conversion to bf16-transposed forms. One-shot, tiny.
// ---------------------------------------------------------------------------
__global__ __launch_bounds__(256) void convert_weights(
    const float* __restrict__ d1W, const float* __restrict__ d2W,
    const float* __restrict__ pwW, const float* __restrict__ d2Ws,
    __hip_bfloat16* __restrict__ d1Wt, __hip_bfloat16* __restrict__ d2Wt,
    __hip_bfloat16* __restrict__ pwWt, __hip_bfloat16* __restrict__ d2pWt) {
    const int t = blockIdx.x * 256 + threadIdx.x;
    if (t < 65536) {
        const int k = t >> 8, n = t & 255;
        d1Wt[n * 256 + k] = __float2bfloat16(d1W[t]);
        d2Wt[n * 256 + k] = __float2bfloat16(d2W[t]);
    }
    if (t < 24576) {
        const int k = t >> 7, n = t & 127;
        pwWt[n * 192 + k] = __float2bfloat16(pwW[t]);
    }
    if (t < 1024) {
        const int q = t >> 5, c = t & 31;
        d2pWt[c * 32 + q] = __float2bfloat16(d2Ws[t]);
    }
}

// ---------------------------------------------------------------------------
// bf16 MFMA GEMM (R7 winner): out = post(A @ Wt^T + bias), Wt pre-transposed.
// Tile 128x128, BK=32, 4 waves.
// ---------------------------------------------------------------------------
template <int ACT, int BN_, int OUTB>
__global__ __launch_bounds__(256) void mfma_gemm(
    const __hip_bfloat16* __restrict__ A, const __hip_bfloat16* __restrict__ Wt,
    const float* __restrict__ bias, const float* __restrict__ gamma,
    const float* __restrict__ beta, void* __restrict__ outp, int K, int Ncols) {
    __shared__ __bf16 As[128][40];
    __shared__ __bf16 Bs[128][40];
    const int tid = threadIdx.x;
    const int w = tid >> 6, l = tid & 63;
    const int wm = w >> 1, wn = w & 1;
    const long row0 = (long)blockIdx.x * 128;
    const int col0 = blockIdx.y * 128;
    const int sr = tid >> 1, sh = tid & 1;
    const int fr = l & 15, kg = (l >> 4) * 8;
    f32x4 acc[4][4] = {};
    const __hip_bfloat16* __restrict__ ap = A + (row0 + sr) * (long)K + sh * 16;
    const __hip_bfloat16* __restrict__ bp =
        Wt + (long)(col0 + sr) * K + sh * 16;
    for (int k0 = 0; k0 < K; k0 += 32) {
        const uint4 av0 = *reinterpret_cast<const uint4*>(ap + k0);
        const uint4 av1 = *reinterpret_cast<const uint4*>(ap + k0 + 8);
        const uint4 bv0 = *reinterpret_cast<const uint4*>(bp + k0);
        const uint4 bv1 = *reinterpret_cast<const uint4*>(bp + k0 + 8);
        *reinterpret_cast<uint4*>(&As[sr][sh * 16]) = av0;
        *reinterpret_cast<uint4*>(&As[sr][sh * 16 + 8]) = av1;
        *reinterpret_cast<uint4*>(&Bs[sr][sh * 16]) = bv0;
        *reinterpret_cast<uint4*>(&Bs[sr][sh * 16 + 8]) = bv1;
        __syncthreads();
        bf16x8 af[4], bfv[4];
#pragma unroll
        for (int mt = 0; mt < 4; ++mt)
            af[mt] =
                *reinterpret_cast<const bf16x8*>(&As[wm * 64 + mt * 16 + fr][kg]);
#pragma unroll
        for (int nt = 0; nt < 4; ++nt)
            bfv[nt] =
                *reinterpret_cast<const bf16x8*>(&Bs[wn * 64 + nt * 16 + fr][kg]);
#pragma unroll
        for (int mt = 0; mt < 4; ++mt)
#pragma unroll
            for (int nt = 0; nt < 4; ++nt)
                acc[mt][nt] = __builtin_amdgcn_mfma_f32_16x16x32_bf16(
                    af[mt], bfv[nt], acc[mt][nt], 0, 0, 0);
        __syncthreads();
    }
    const int rg = (l >> 4) * 4;
#pragma unroll
    for (int nt = 0; nt < 4; ++nt) {
        const int col = col0 + wn * 64 + nt * 16 + fr;
        const float bb = bias[col];
        const float gs = BN_ ? gamma[col] * RS : 0.0f;
        const float bt = BN_ ? beta[col] : 0.0f;
#pragma unroll
        for (int mt = 0; mt < 4; ++mt) {
#pragma unroll
            for (int r = 0; r < 4; ++r) {
                const long row = row0 + wm * 64 + mt * 16 + rg + r;
                float v = acc[mt][nt][r] + bb;
                if (ACT) v = eluf(v);
                if (BN_) v = v * gs + bt;
                if (OUTB)
                    reinterpret_cast<__hip_bfloat16*>(outp)[row * Ncols + col] =
                        __float2bfloat16(v);
                else
                    reinterpret_cast<float*>(outp)[row * Ncols + col] = v;
            }
        }
    }
}

// ---------------------------------------------------------------------------
// Setup: pts_local (f32 store) + Xc (bf16 store). 16 pts/block, grid 2048.
// ---------------------------------------------------------------------------
__global__ __launch_bounds__(256) void setup_kernel(
    const float* __restrict__ rep_pts, const float* __restrict__ pts,
    const int* __restrict__ pts_idx, const float* __restrict__ xt_cW,
    const float* __restrict__ xt_cb, float* __restrict__ pts_local,
    __hip_bfloat16* __restrict__ Xc) {
    __shared__ float cwT[48][256];
    __shared__ float pl2[16][48];
    __shared__ float cb_s[256];
    const int tid = threadIdx.x;
    const long gp0 = (long)blockIdx.x * 16;
#pragma unroll
    for (int i = 0; i < 48; ++i) {
        const int e = i * 256 + tid;
        const int o = e / 48, r = e - o * 48;
        cwT[r][o] = xt_cW[e];
    }
    cb_s[tid] = xt_cb[tid];
    {
        const int pt = tid >> 4, k = tid & 15;
        const long gp = gp0 + pt;
        const int n = (int)(gp >> 11);
        const int idx = pts_idx[gp * 32 + 2 * k];
        const float* ps = pts + ((long)n * 8192 + idx) * 3;
        const float* rs = rep_pts + gp * 3;
        float* plo = pts_local + gp * 48 + k * 3;
#pragma unroll
        for (int d = 0; d < 3; ++d) {
            const float v = ps[d] - rs[d];
            pl2[pt][d * 16 + k] = v;
            plo[d] = v;
        }
    }
    __syncthreads();
    const int o = tid;
    for (int pt = 0; pt < 16; ++pt) {
        float acc = cb_s[o];
#pragma unroll
        for (int i = 0; i < 48; ++i) acc = fmaf(pl2[pt][i], cwT[i][o], acc);
        Xc[(gp0 + pt) * 256 + o] = __float2bfloat16(eluf(acc));
    }
}

// ---------------------------------------------------------------------------
// Final per-point stage v7: v6 + bf16 fts_l gather + XCD-aware block swizzle.
// Block = 256 = 4 waves = 4 points; grid 8192 (bijective swizzle, 8192%8==0:
// XCD x handles contiguous points [x*4096,(x+1)*4096) = 2 batches -> the two
// 1 MB bf16 fts_l slices fit the XCD's 4 MB L2).
// NOTE: no 2nd __launch_bounds__ arg (R4: (256,4) clamp -> 64 VGPR spill).
// ---------------------------------------------------------------------------
__global__ __launch_bounds__(256) void final_stage_kernel(
    const __hip_bfloat16* __restrict__ X2B,  // [32768][256] bf16
    const float* __restrict__ pts_local,     // [32768][48] (k*3+d)
    const int* __restrict__ pts_idx,
    const __hip_bfloat16* __restrict__ fts_lB,  // [131072][64] bf16
    const float* __restrict__ d1_W, const float* __restrict__ d1_b,
    const float* __restrict__ d1_g, const float* __restrict__ d1_bt,
    const __hip_bfloat16* __restrict__ d2pWt,  // [32 c][32 q] bf16
    const float* __restrict__ d2_b, const float* __restrict__ d2_g,
    const float* __restrict__ d2_bt, const float* __restrict__ dw_W,
    const float* __restrict__ dw_b,
    __hip_bfloat16* __restrict__ dw_out)  // [32768][192] bf16
{
    __shared__ __bf16 fcat[4][96][24];  // wave-private
    __shared__ float pl_s[4][48];       // wave-private

    const int tid = threadIdx.x;
    const int w = tid >> 6, l = tid & 63;
    // XCD-aware swizzle: consecutive orig-blocks round-robin XCDs; regroup so
    // each XCD gets a contiguous 1024-block chunk (= 4096 points = 2 batches).
    const int obid = blockIdx.x;
    const int bid = (obid & 7) * 1024 + (obid >> 3);
    const int gp = bid * 4 + w;
    const int ugp = __builtin_amdgcn_readfirstlane(gp);  // wave-uniform
    const int n = ugp >> 11;
    const int fr = l & 15;        // fragment row/col within 16
    const int kg = (l >> 4) * 8;  // k-chunk start: 0,8,16,24
    const int kk = kg & 15;       // wrapped: 0,8
    const unsigned msk = (l < 32) ? 0xFFFFFFFFu : 0u;
    const int rg4 = (l >> 4) * 4;

    if (l < 48) pl_s[w][l] = pts_local[(long)ugp * 48 + l];

    // ---- fts gather: lane owns bf16 col colg, 16 rows (idx via s_load) ----
    const int* __restrict__ ip = pts_idx + (long)ugp * 32;
    const int colg = (l < 32) ? (32 + l) : (l - 32);
    const __hip_bfloat16* __restrict__ fbase =
        fts_lB + (long)n * 8192 * 64 + colg;
    unsigned fg[16];
#pragma unroll
    for (int j = 0; j < 16; ++j)
        fg[j] = *reinterpret_cast<const unsigned short*>(
            &fbase[(long)ip[2 * j] * 64]);

    // ---- l0 row-owner into A-frag: lane = row fr, k-cols kg..kg+7 ----
    bf16x8 a_l0;
    {
        const float p0 = pl_s[w][fr * 3 + 0];
        const float p1 = pl_s[w][fr * 3 + 1];
        const float p2 = pl_s[w][fr * 3 + 2];
#pragma unroll
        for (int jj = 0; jj < 8; ++jj) {
            const int q = kg + jj;
            float a = d1_b[q];
            a = fmaf(p0, d1_W[q], a);
            a = fmaf(p1, d1_W[32 + q], a);
            a = fmaf(p2, d1_W[64 + q], a);
            a = eluf(a);
            a = a * (d1_g[q] * RS) + d1_bt[q];
            a_l0[jj] = (__bf16)a;
        }
    }

    // ---- lifted = l0 @ d2_W via 2 MFMA (K=32 exact) ----
    {
        const bf16x8 b0 =
            *reinterpret_cast<const bf16x8*>(d2pWt + (0 + fr) * 32 + kg);
        const bf16x8 b1 =
            *reinterpret_cast<const bf16x8*>(d2pWt + (16 + fr) * 32 + kg);
        f32x4 lif0 = {}, lif1 = {};
        lif0 = __builtin_amdgcn_mfma_f32_16x16x32_bf16(a_l0, b0, lif0, 0, 0, 0);
        lif1 = __builtin_amdgcn_mfma_f32_16x16x32_bf16(a_l0, b1, lif1, 0, 0, 0);
#pragma unroll
        for (int f = 0; f < 2; ++f) {
            const int c = f * 16 + fr;
            const float bb = d2_b[c], gs = d2_g[c] * RS, bt = d2_bt[c];
            const f32x4 dd = f ? lif1 : lif0;
            unsigned short pk[4];
#pragma unroll
            for (int r = 0; r < 4; ++r) {
                float v = dd[r] + bb;
                v = eluf(v) * gs + bt;
                const __bf16 h = (__bf16)v;
                pk[r] = *reinterpret_cast<const unsigned short*>(&h);
            }
            *reinterpret_cast<uint2*>(&fcat[w][c][rg4]) =
                make_uint2((unsigned)pk[0] | ((unsigned)pk[1] << 16),
                           (unsigned)pk[2] | ((unsigned)pk[3] << 16));
        }
    }

    // ---- fg (already bf16 bits) -> fcat[32+colg][0..15] (2 x b128) ----
    {
        const uint4 lo = make_uint4(fg[0] | (fg[1] << 16), fg[2] | (fg[3] << 16),
                                    fg[4] | (fg[5] << 16), fg[6] | (fg[7] << 16));
        const uint4 hi =
            make_uint4(fg[8] | (fg[9] << 16), fg[10] | (fg[11] << 16),
                       fg[12] | (fg[13] << 16), fg[14] | (fg[15] << 16));
        *reinterpret_cast<uint4*>(&fcat[w][32 + colg][0]) = lo;
        *reinterpret_cast<uint4*>(&fcat[w][32 + colg][8]) = hi;
    }

    // ---- A-frag: X row fr, k=kk..kk+7 from bf16 X2 (zero for lanes>=32) ----
    u32x4 axu =
        *reinterpret_cast<const u32x4*>(X2B + (long)ugp * 256 + fr * 16 + kk);
    axu &= msk;
    const bf16x8 ax = *reinterpret_cast<const bf16x8*>(&axu);

    // ---- fts_X: 6 B-frags from fcat + 6 MFMA ----
    f32x4 acc[6];
#pragma unroll
    for (int f = 0; f < 6; ++f) acc[f] = (f32x4){};
#pragma unroll
    for (int f = 0; f < 6; ++f) {
        u32x4 bu = *reinterpret_cast<const u32x4*>(&fcat[w][f * 16 + fr][kk]);
        bu &= msk;  // zero k>=16 (also kills uninit-LDS NaN)
        const bf16x8 bf = *reinterpret_cast<const bf16x8*>(&bu);
        acc[f] = __builtin_amdgcn_mfma_f32_16x16x32_bf16(ax, bf, acc[f], 0, 0, 0);
    }

    // ---- dw: partials over rows rg4..rg4+3, butterfly over lane groups ----
    float dwv[6][2];
#pragma unroll
    for (int f = 0; f < 6; ++f) {
        const int c = f * 16 + fr;
        const float4 w0 = *reinterpret_cast<const float4*>(dw_W + c * 32 + rg4);
        const float4 w1 =
            *reinterpret_cast<const float4*>(dw_W + c * 32 + 16 + rg4);
        float p0 = acc[f][0] * w0.x;
        p0 = fmaf(acc[f][1], w0.y, p0);
        p0 = fmaf(acc[f][2], w0.z, p0);
        p0 = fmaf(acc[f][3], w0.w, p0);
        float p1 = acc[f][0] * w1.x;
        p1 = fmaf(acc[f][1], w1.y, p1);
        p1 = fmaf(acc[f][2], w1.z, p1);
        p1 = fmaf(acc[f][3], w1.w, p1);
        p0 += __shfl_xor(p0, 16);
        p0 += __shfl_xor(p0, 32);
        p1 += __shfl_xor(p1, 16);
        p1 += __shfl_xor(p1, 32);
        dwv[f][0] = p0;
        dwv[f][1] = p1;
    }
    if (l < 16) {
#pragma unroll
        for (int f = 0; f < 6; ++f) {
            const int c = f * 16 + l;
            __hip_bfloat162 pk;
            pk.x = __float2bfloat16(dwv[f][0] + dw_b[2 * c + 0]);
            pk.y = __float2bfloat16(dwv[f][1] + dw_b[2 * c + 1]);
            *reinterpret_cast<__hip_bfloat162*>(dw_out + (long)gp * 192 +
                                                2 * c) = pk;
        }
    }
}

extern "C" void kernel_launch(void* const* d_in, const int* in_sizes, int n_in,
                              void* d_out, int out_size, void* d_ws,
                              size_t ws_size, hipStream_t stream) {
    const float* rep_pts = (const float*)d_in[0];
    const float* pts = (const float*)d_in[1];
    const float* fts = (const float*)d_in[2];
    const int* pts_idx = (const int*)d_in[3];
    const float* dense_W = (const float*)d_in[4];
    const float* dense_b = (const float*)d_in[5];
    const float* dense_g = (const float*)d_in[6];
    const float* dense_bt = (const float*)d_in[7];
    const float* d1_W = (const float*)d_in[8];
    const float* d1_b = (const float*)d_in[9];
    const float* d1_g = (const float*)d_in[10];
    const float* d1_bt = (const float*)d_in[11];
    const float* d2_W = (const float*)d_in[12];
    const float* d2_b = (const float*)d_in[13];
    const float* d2_g = (const float*)d_in[14];
    const float* d2_bt = (const float*)d_in[15];
    const float* xt_cW = (const float*)d_in[16];
    const float* xt_cb = (const float*)d_in[17];
    const float* xt_d1W = (const float*)d_in[18];
    const float* xt_d1b = (const float*)d_in[19];
    const float* xt_d2W = (const float*)d_in[20];
    const float* xt_d2b = (const float*)d_in[21];
    const float* dw_W = (const float*)d_in[22];
    const float* dw_b = (const float*)d_in[23];
    const float* pw_W = (const float*)d_in[24];
    const float* pw_b = (const float*)d_in[25];
    const float* sep_g = (const float*)d_in[26];
    const float* sep_bt = (const float*)d_in[27];

    float* ws = (float*)d_ws;
    // layout (f32 slots). fts_l now bf16 (half the old slot). dwB overlays XcB.
    __hip_bfloat16* fts_lB = (__hip_bfloat16*)ws;              // 8388608 bf16
    __hip_bfloat16* X2Bb = (__hip_bfloat16*)(ws + 8388608);    // 8388608 bf16
    __hip_bfloat16* XcB = (__hip_bfloat16*)(ws + 16777216);    // 8388608 bf16
    __hip_bfloat16* dwB = (__hip_bfloat16*)(ws + 16777216);    // 6291456 bf16
    __hip_bfloat16* X1B = (__hip_bfloat16*)(ws + 20971520);    // 8388608 bf16
    float* pl = ws + 25165824;                                 // 1572864 f32
    __hip_bfloat16* d1Wt = (__hip_bfloat16*)(ws + 26738688);   // 65536 bf16
    __hip_bfloat16* d2Wt = (__hip_bfloat16*)(ws + 26771456);   // 65536 bf16
    __hip_bfloat16* pwWt = (__hip_bfloat16*)(ws + 26804224);   // 24576 bf16
    __hip_bfloat16* d2pWt = (__hip_bfloat16*)(ws + 26816512);  // 1024 bf16

    // 0) weight convert+transpose to bf16
    convert_weights<<<256, 256, 0, stream>>>(xt_d1W, xt_d2W, pw_W, d2_W, d1Wt,
                                             d2Wt, pwWt, d2pWt);

    // 1) fts_l = bn(elu(fts @ dense_W + b))  f32 GEMM -> bf16 out
    gemm_bias_act<1, 1, 1><<<dim3(2048, 1), 256, 0, stream>>>(
        fts, dense_W, dense_b, dense_g, dense_bt, fts_lB, 64, 64);

    // 2) pts_local + Xc (bf16)
    setup_kernel<<<2048, 256, 0, stream>>>(rep_pts, pts, pts_idx, xt_cW, xt_cb,
                                           pl, XcB);

    // 3) X1 = elu(Xc @ xt_d1W + b)  bf16 MFMA -> bf16
    mfma_gemm<1, 0, 1><<<dim3(256, 2), 256, 0, stream>>>(
        XcB, d1Wt, xt_d1b, nullptr, nullptr, X1B, 256, 256);

    // 4) X2 = X1 @ xt_d2W + b  bf16 MFMA -> bf16
    mfma_gemm<0, 0, 1><<<dim3(256, 2), 256, 0, stream>>>(
        X1B, d2Wt, xt_d2b, nullptr, nullptr, X2Bb, 256, 256);

    // 5) lifted/gather/fts_X/dw -> dwB (bf16)
    final_stage_kernel<<<8192, 256, 0, stream>>>(
        X2Bb, pl, pts_idx, fts_lB, d1_W, d1_b, d1_g, d1_bt, d2pWt, d2_b, d2_g,
        d2_bt, dw_W, dw_b, dwB);

    // 6) out = bn(elu(dw @ pw_W + pw_b))  bf16 MFMA -> f32
    mfma_gemm<1, 1, 0><<<dim3(256, 1), 256, 0, stream>>>(
        dwB, pwWt, pw_b, sep_g, sep_bt, d_out, 192, 128);
}